// Round 1
// baseline (229.514 us; speedup 1.0000x reference)
//
#include <hip/hip_runtime.h>
#include <hip/hip_bf16.h>

// LSTM_80960133529703: B=16384, T=24, F=7, H=8, L=4; dense 192->1024->2048->4.
// R9: gemm2 rewritten as the verified 256^2 8-phase template (plain HIP):
//     256x256 tile, BK=64, 512 thr / 8 waves (2Mx4N, 128x64 per wave),
//     mfma_f32_16x16x32_bf16, 2-K-tile LDS double buffer (128 KiB),
//     chunk-XOR swizzle (pre-swizzled global src + swizzled ds_read),
//     counted s_waitcnt vmcnt(4) at phases 4/8 (never 0 in steady state),
//     s_setprio(1) around each 16-MFMA cluster, raw s_barrier (no vmcnt
//     drain at barriers). Fused relu+W3 epilogue as 4 LDS slab passes.
//     gemm1 (K=192: too shallow to fill the pipeline) and pre_kernel kept.
// Schedule (iter i computes K-tiles 2i in buf0, 2i+1 in buf1):
//   region freed:  buf0.A after P3, buf0.B after P2, buf1.A after P7, buf1.B after P6
//   stage: P1 b1.Ah0<-2i+1  P2 b1.Ah1<-2i+1  P3 b0.Bh0<-2i+2  P4 b0.Bh1<-2i+2
//          P5 b0.Ah0<-2i+2  P6 b0.Ah1<-2i+2  P7 b1.Bh0<-2i+3  P8 b1.Bh1<-2i+3
//   vmcnt(4)@P4: prev{P7,P8}+{P1,P2} landed  -> P5..P7 reads of buf1 safe
//   vmcnt(4)@P8: {P3..P6} landed             -> next-iter P1..P3 reads of buf0 safe
//   last iter: stages P1/P2 only, vmcnt(0)@P4.
// ws: Y @0 | H1 @6291456 | W1b @39845888 | W2b @40239104
typedef __attribute__((ext_vector_type(4))) float f32x4;
typedef __attribute__((ext_vector_type(16))) float f32x16;
typedef __attribute__((ext_vector_type(2))) float f32x2;
typedef __attribute__((ext_vector_type(8))) short bf16x8;

__device__ __forceinline__ ushort f2bf(float f) {
    union { float f; uint u; } v; v.f = f;
    uint u = v.u;
    return (ushort)((u + 0x7fffu + ((u >> 16) & 1u)) >> 16);   // RNE
}
__device__ __forceinline__ float sigm(float x) {
    return __builtin_amdgcn_rcpf(1.0f + __builtin_amdgcn_exp2f(x * -1.442695040888963f));
}
__device__ __forceinline__ float tanh_(float x) {
    return 2.0f * __builtin_amdgcn_rcpf(1.0f + __builtin_amdgcn_exp2f(x * -2.885390081777927f)) - 1.0f;
}

typedef const __attribute__((address_space(1))) unsigned int ga_u32;
typedef __attribute__((address_space(3))) unsigned int lds_u32;
__device__ __forceinline__ void g2l16(const void* g, void* l) {
    __builtin_amdgcn_global_load_lds((ga_u32*)(unsigned long long)g,
                                     (lds_u32*)(unsigned int)(unsigned long long)l,
                                     16, 0, 0);
}

// ---------------------------------------------------------------- LSTM ----
struct LstmW {
    const float* wih[4];
    const float* whh[4];
    const float* bih[4];
    const float* bhh[4];
};

__device__ __forceinline__ void gates8p(const f32x2 w01[8], const f32x2 w23[8],
                                        const float xv8[8], f32x2& a01, f32x2& a23) {
#pragma unroll
    for (int k = 0; k < 8; ++k) {
        f32x2 xv = {xv8[k], xv8[k]};
        a01 += w01[k] * xv;
        a23 += w23[k] * xv;
    }
}
__device__ __forceinline__ void cellup(f32x2 a01, f32x2 a23, float& h, float& c) {
    c = sigm(a01.y) * c + sigm(a01.x) * tanh_(a23.x);
    h = sigm(a23.y) * tanh_(c);
}
__device__ __forceinline__ void ld8(const float* p, float v[8]) {
    float4 a = *(const float4*)p;
    float4 b = *(const float4*)(p + 4);
    v[0] = a.x; v[1] = a.y; v[2] = a.z; v[3] = a.w;
    v[4] = b.x; v[5] = b.y; v[6] = b.z; v[7] = b.w;
}

// blocks [0,512): LSTM; blocks [512, 512+560): weight cvt fp32->bf16 (+ out init)
__global__ __launch_bounds__(256) void pre_kernel(const float* __restrict__ x, LstmW p,
                                                  ushort* __restrict__ Y,
                                                  const float* __restrict__ W1,
                                                  const float* __restrict__ W2,
                                                  ushort* __restrict__ W1b,
                                                  ushort* __restrict__ W2b,
                                                  const float* __restrict__ b3,
                                                  float* __restrict__ out) {
    __shared__ float xs[32 * 168];
    __shared__ float hb[32 * 200];

    const int tid = threadIdx.x;
    if (blockIdx.x >= 512) {
        const int tg = (blockIdx.x - 512) * 256 + tid;
        if (tg < 16384) {
            float4 bv = {b3[0], b3[1], b3[2], b3[3]};
            ((float4*)out)[tg] = bv;
        }
#pragma unroll
        for (int s = 0; s < 4; ++s) {
            int i = tg + s * 143360;
            const float4* src; ushort4* dst; int off;
            if (i < 49152) { src = (const float4*)W1; dst = (ushort4*)W1b; off = i; }
            else { src = (const float4*)W2; dst = (ushort4*)W2b; off = i - 49152; }
            float4 v = src[off];
            ushort4 r; r.x = f2bf(v.x); r.y = f2bf(v.y); r.z = f2bf(v.z); r.w = f2bf(v.w);
            dst[off] = r;
        }
        return;
    }

    const int e0 = blockIdx.x * 32;
    {
        const float4* s = (const float4*)(x + (size_t)e0 * 168);
        float4* d = (float4*)xs;
        for (int i = tid; i < 1344; i += 256) d[i] = s[i];
    }
    __syncthreads();

    const int el = tid >> 3, j = tid & 7;
    float* hr = hb + el * 200;
    const float* xr = xs + el * 168;

    f32x2 wx01[8], wx23[8], wh01[8], wh23[8], b01, b23;

    // ---- layer 0 (in = 7) ----
    {
        const float* Wih = p.wih[0];
        const float* Whh = p.whh[0];
#pragma unroll
        for (int k = 0; k < 7; ++k) {
            wx01[k] = {Wih[(0 + j) * 7 + k], Wih[(8 + j) * 7 + k]};
            wx23[k] = {Wih[(16 + j) * 7 + k], Wih[(24 + j) * 7 + k]};
        }
#pragma unroll
        for (int k = 0; k < 8; ++k) {
            wh01[k] = {Whh[(0 + j) * 8 + k], Whh[(8 + j) * 8 + k]};
            wh23[k] = {Whh[(16 + j) * 8 + k], Whh[(24 + j) * 8 + k]};
        }
        b01 = {p.bih[0][j] + p.bhh[0][j], p.bih[0][8 + j] + p.bhh[0][8 + j]};
        b23 = {p.bih[0][16 + j] + p.bhh[0][16 + j], p.bih[0][24 + j] + p.bhh[0][24 + j]};

        float h = 0.f, c = 0.f;
        {
            f32x2 a01 = b01, a23 = b23;
#pragma unroll
            for (int k = 0; k < 7; ++k) {
                f32x2 xv = {xr[k], xr[k]};
                a01 += wx01[k] * xv; a23 += wx23[k] * xv;
            }
            cellup(a01, a23, h, c);
            hr[j] = h;
        }
        for (int t = 1; t < 24; ++t) {
            f32x2 a01 = b01, a23 = b23;
#pragma unroll
            for (int k = 0; k < 7; ++k) {
                f32x2 xv = {xr[t * 7 + k], xr[t * 7 + k]};
                a01 += wx01[k] * xv; a23 += wx23[k] * xv;
            }
            float hp[8]; ld8(&hr[(t - 1) * 8], hp);
            gates8p(wh01, wh23, hp, a01, a23);
            cellup(a01, a23, h, c);
            hr[t * 8 + j] = h;
        }
    }

    // ---- layers 1..3 ----
#pragma unroll
    for (int l = 1; l < 4; ++l) {
        const float* Wih = p.wih[l];
        const float* Whh = p.whh[l];
#pragma unroll
        for (int k = 0; k < 8; ++k) {
            wx01[k] = {Wih[(0 + j) * 8 + k], Wih[(8 + j) * 8 + k]};
            wx23[k] = {Wih[(16 + j) * 8 + k], Wih[(24 + j) * 8 + k]};
            wh01[k] = {Whh[(0 + j) * 8 + k], Whh[(8 + j) * 8 + k]};
            wh23[k] = {Whh[(16 + j) * 8 + k], Whh[(24 + j) * 8 + k]};
        }
        b01 = {p.bih[l][j] + p.bhh[l][j], p.bih[l][8 + j] + p.bhh[l][8 + j]};
        b23 = {p.bih[l][16 + j] + p.bhh[l][16 + j], p.bih[l][24 + j] + p.bhh[l][24 + j]};

        float h = 0.f, c = 0.f;
        {
            float xin[8]; ld8(&hr[0], xin);
            f32x2 a01 = b01, a23 = b23;
            gates8p(wx01, wx23, xin, a01, a23);
            cellup(a01, a23, h, c);
            hr[j] = h;
            if (l == 3) Y[((size_t)(e0 + el) * 24) * 8 + j] = f2bf(h);
        }
        for (int t = 1; t < 24; ++t) {
            float xin[8]; ld8(&hr[t * 8], xin);
            float hp[8];  ld8(&hr[(t - 1) * 8], hp);
            f32x2 a01 = b01, a23 = b23;
            gates8p(wx01, wx23, xin, a01, a23);
            gates8p(wh01, wh23, hp, a01, a23);
            cellup(a01, a23, h, c);
            hr[t * 8 + j] = h;
            if (l == 3) Y[((size_t)(e0 + el) * 24 + t) * 8 + j] = f2bf(h);
        }
    }
}

// ------------------------------------------------------- gemm1 (K=192) ----
// Tile 128x128, BK=64, 4 waves; wave tile 64x64 as 2x2 of mfma_32x32x16.
// Unchanged from R8 (K too shallow for the 8-phase pipeline).
template <int KDIM>
__device__ __forceinline__ void gemm_body(const ushort* __restrict__ A,
                                          const ushort* __restrict__ W,
                                          const float* __restrict__ bias,
                                          ushort* __restrict__ Hout, int N) {
    __shared__ alignas(16) ushort smem[16384];
    ushort* As = smem;            // [128][64] swizzled
    ushort* Ws = smem + 8192;

    const int tid = threadIdx.x;
    const int m0 = blockIdx.x * 128;
    const int n0 = blockIdx.y * 128;
    const int lane = tid & 63;
    const int wv = tid >> 6;
    const int wm = (wv & 1) * 64;
    const int wn = (wv >> 1) * 64;
    const int l31 = lane & 31;
    const int kh = lane >> 5;

    // staging: per wave, 4 calls/tensor; call c: rows wv*32 + c*8 + lrow
    const int lrow = lane >> 3;
    const int lchunk = (lane & 7) ^ lrow;          // XOR swizzle at source
    const ushort* Ag = A + (size_t)(m0 + wv * 32 + lrow) * KDIM + lchunk * 8;
    const ushort* Wg = W + (size_t)(n0 + wv * 32 + lrow) * KDIM + lchunk * 8;
    ushort* Ald = As + wv * 2048;
    ushort* Wld = Ws + wv * 2048;

    const int r7 = l31 & 7;
    const int arow0 = (wm + l31) * 64;        // mi=0; mi=1 adds 32*64
    const int brow0 = (wn + l31) * 64;

    f32x16 acc[2][2];
#pragma unroll
    for (int mi = 0; mi < 2; ++mi)
#pragma unroll
        for (int ni = 0; ni < 2; ++ni)
#pragma unroll
            for (int r = 0; r < 16; ++r) acc[mi][ni][r] = 0.f;

    for (int k0 = 0; k0 < KDIM; k0 += 64) {
#pragma unroll
        for (int c = 0; c < 4; ++c)
            g2l16(Ag + (size_t)c * 8 * KDIM + k0, Ald + c * 512);
#pragma unroll
        for (int c = 0; c < 4; ++c)
            g2l16(Wg + (size_t)c * 8 * KDIM + k0, Wld + c * 512);
        __syncthreads();

#pragma unroll
        for (int ks = 0; ks < 4; ++ks) {
            const int ck = ((ks * 2 + kh) ^ r7) * 8;
            bf16x8 afr[2], bfr[2];
#pragma unroll
            for (int mi = 0; mi < 2; ++mi)
                afr[mi] = *(const bf16x8*)&As[arow0 + mi * 2048 + ck];
#pragma unroll
            for (int ni = 0; ni < 2; ++ni)
                bfr[ni] = *(const bf16x8*)&Ws[brow0 + ni * 2048 + ck];
#pragma unroll
            for (int mi = 0; mi < 2; ++mi)
#pragma unroll
                for (int ni = 0; ni < 2; ++ni)
                    acc[mi][ni] = __builtin_amdgcn_mfma_f32_32x32x16_bf16(afr[mi], bfr[ni],
                                                                         acc[mi][ni], 0, 0, 0);
        }
        __syncthreads();
    }

#pragma unroll
    for (int ni = 0; ni < 2; ++ni) {
        const int col = n0 + wn + ni * 32 + l31;
        const float b = bias[col];
#pragma unroll
        for (int mi = 0; mi < 2; ++mi)
#pragma unroll
            for (int r = 0; r < 16; ++r) {
                const int row = m0 + wm + mi * 32 + (r & 3) + 8 * (r >> 2) + 4 * kh;
                Hout[(size_t)row * N + col] = f2bf(fmaxf(acc[mi][ni][r] + b, 0.f));
            }
    }
}

__global__ __launch_bounds__(256, 4) void gemm1_kernel(const ushort* __restrict__ A,
                                                       const ushort* __restrict__ W,
                                                       const float* __restrict__ bias,
                                                       ushort* __restrict__ Hout, int N) {
    gemm_body<192>(A, W, bias, Hout, N);
}

// ---------------------------------------------- gemm2: 256^2 8-phase -----
__device__ __forceinline__ void ld_ah(const ushort* base, int off, bf16x8 fr[8],
                                      int pc0, int pc1) {
#pragma unroll
    for (int mi = 0; mi < 4; ++mi) {
        const ushort* p = base + off + mi * 1024;
        fr[mi * 2 + 0] = *(const bf16x8*)(p + pc0);
        fr[mi * 2 + 1] = *(const bf16x8*)(p + pc1);
    }
}
__device__ __forceinline__ void ld_bh(const ushort* base, int off, bf16x8 fr[4],
                                      int pc0, int pc1) {
#pragma unroll
    for (int ni = 0; ni < 2; ++ni) {
        const ushort* p = base + off + ni * 1024;
        fr[ni * 2 + 0] = *(const bf16x8*)(p + pc0);
        fr[ni * 2 + 1] = *(const bf16x8*)(p + pc1);
    }
}
// one C-quadrant (4 mi x 2 ni) over the full K=64 tile (2 ks)
template <int QA, int QB>
__device__ __forceinline__ void mma_quad(f32x4 acc[8][4], const bf16x8 afr[8],
                                         const bf16x8 bfr[4]) {
#pragma unroll
    for (int ks = 0; ks < 2; ++ks)
#pragma unroll
        for (int mi = 0; mi < 4; ++mi)
#pragma unroll
            for (int ni = 0; ni < 2; ++ni)
                acc[QA * 4 + mi][QB * 2 + ni] = __builtin_amdgcn_mfma_f32_16x16x32_bf16(
                    afr[mi * 2 + ks], bfr[ni * 2 + ks], acc[QA * 4 + mi][QB * 2 + ni],
                    0, 0, 0);
}

#define SBAR() __builtin_amdgcn_s_barrier()

__global__ __launch_bounds__(512) void gemm2_kernel(const ushort* __restrict__ A,
                                                    const ushort* __restrict__ W,
                                                    const float* __restrict__ bias,
                                                    const float* __restrict__ W3,
                                                    float* __restrict__ outf) {
    // LDS: 2 K-tile double buffer, [256 rows][64 k] bf16 per tensor per buf.
    // A0 @0, B0 @16384, A1 @32768, B1 @49152 (ushort offsets). 128 KiB.
    __shared__ alignas(16) ushort smem[65536];
    __shared__ alignas(16) float w3s[1040];   // W3[4][256] at pitch 260

    const int tid = threadIdx.x;
    // bijective XCD swizzle (512 % 8 == 0): each XCD gets 8 consecutive
    // bm panels x all 8 bn -> A panel + B slab L2-resident per XCD.
    const int wg = ((int)blockIdx.x & 7) * 64 + ((int)blockIdx.x >> 3);
    const int m0 = (wg >> 3) << 8;
    const int n0 = (wg & 7) << 8;

    const int lane = tid & 63;
    const int wv = tid >> 6;

    // ---- staging addressing (pre-swizzled global source, linear LDS dest)
    const int lrow = tid >> 3;                         // 0..63 rows per call
    const int lc8 = ((tid & 7) ^ (lrow & 7)) << 3;     // swizzled k-chunk
    const ushort* Ag = A + (size_t)(m0 + lrow) * 1024 + lc8;
    const ushort* Bg = W + (size_t)(n0 + lrow) * 1024 + lc8;
    ushort* const sA0 = smem;
    ushort* const sB0 = smem + 16384;
    ushort* const sA1 = smem + 32768;
    ushort* const sB1 = smem + 49152;
    const int srow64 = (wv << 3) * 64;                 // wave's LDS row base

    // ---- frag addressing: phys chunk = logical ^ (row&7)
    const int l15 = lane & 15, kq = lane >> 4, r7 = l15 & 7;
    const int pc0 = (kq ^ r7) << 3;                    // ks=0
    const int pc1 = ((4 + kq) ^ r7) << 3;              // ks=1
    const int wM = wv >> 2, wN = wv & 3;               // 2M x 4N waves
    const int aOff = (wM * 128 + l15) * 64;            // + frag*1024
    const int bOff = (wN * 64 + l15) * 64;

    auto stA = [&](int buf, int h, int kt) {           // stage A half-tile
        ushort* b = buf ? sA1 : sA0;
#pragma unroll
        for (int c = 0; c < 2; ++c)
            g2l16(Ag + (size_t)(h * 128 + c * 64) * 1024 + kt * 64,
                  b + (h * 128 + c * 64) * 64 + srow64);
    };
    auto stB = [&](int buf, int h, int kt) {           // stage B half-tile
        ushort* b = buf ? sB1 : sB0;
#pragma unroll
        for (int c = 0; c < 2; ++c)
            g2l16(Bg + (size_t)(h * 128 + c * 64) * 1024 + kt * 64,
                  b + (h * 128 + c * 64) * 64 + srow64);
    };

    f32x4 acc[8][4];
#pragma unroll
    for (int i = 0; i < 8; ++i)
#pragma unroll
        for (int j = 0; j < 4; ++j)
#pragma unroll
            for (int r = 0; r < 4; ++r) acc[i][j][r] = 0.f;

    // W3 -> LDS + bias -> regs (issued before staging; prologue vmcnt(0)
    // drains them so in-loop vmcnt counts are staging-only).
#pragma unroll
    for (int i = 0; i < 2; ++i) {
        int idx = tid + i * 512;
        w3s[(idx >> 8) * 260 + (idx & 255)] = W3[(size_t)(idx >> 8) * 2048 + n0 + (idx & 255)];
    }
    float bias4[4];
#pragma unroll
    for (int ni = 0; ni < 4; ++ni) bias4[ni] = bias[n0 + wN * 64 + ni * 16 + l15];

    // prologue: buf0 (kt 0) full + buf1.B (kt 1); buf1.A comes from P1/P2.
    stA(0, 0, 0); stB(0, 0, 0); stB(0, 1, 0); stA(0, 1, 0);
    stB(1, 0, 1); stB(1, 1, 1);
    asm volatile("s_waitcnt vmcnt(0)" ::: "memory");
    SBAR();

    bf16x8 afr[8], b0r[4], b1r[4];
#pragma unroll 1
    for (int it = 0; it < 8; ++it) {
        const int k1 = 2 * it + 1, k2 = 2 * it + 2, k3 = 2 * it + 3;
        const bool nl = (it < 7);
        // P1: quad(0,0) buf0
        ld_ah(sA0, aOff, afr, pc0, pc1);
        ld_bh(sB0, bOff, b0r, pc0, pc1);
        stA(1, 0, k1);
        SBAR();
        __builtin_amdgcn_s_setprio(1);
        mma_quad<0, 0>(acc, afr, b0r);
        __builtin_amdgcn_s_setprio(0);
        SBAR();
        // P2: quad(0,1) buf0
        ld_bh(sB0, bOff + 2048, b1r, pc0, pc1);
        stA(1, 1, k1);
        SBAR();
        __builtin_amdgcn_s_setprio(1);
        mma_quad<0, 1>(acc, afr, b1r);
        __builtin_amdgcn_s_setprio(0);
        SBAR();
        // P3: quad(1,1) buf0
        ld_ah(sA0, aOff + 4096, afr, pc0, pc1);
        if (nl) stB(0, 0, k2);
        SBAR();
        __builtin_amdgcn_s_setprio(1);
        mma_quad<1, 1>(acc, afr, b1r);
        __builtin_amdgcn_s_setprio(0);
        SBAR();
        // P4: quad(1,0) buf0 | K-tile boundary wait
        if (nl) stB(0, 1, k2);
        SBAR();
        __builtin_amdgcn_s_setprio(1);
        mma_quad<1, 0>(acc, afr, b0r);
        __builtin_amdgcn_s_setprio(0);
        if (nl) { asm volatile("s_waitcnt vmcnt(4)" ::: "memory"); }
        else    { asm volatile("s_waitcnt vmcnt(0)" ::: "memory"); }
        SBAR();
        // P5: quad(1,0) buf1
        ld_ah(sA1, aOff + 4096, afr, pc0, pc1);
        ld_bh(sB1, bOff, b0r, pc0, pc1);
        if (nl) stA(0, 0, k2);
        SBAR();
        __builtin_amdgcn_s_setprio(1);
        mma_quad<1, 0>(acc, afr, b0r);
        __builtin_amdgcn_s_setprio(0);
        SBAR();
        // P6: quad(1,1) buf1
        ld_bh(sB1, bOff + 2048, b1r, pc0, pc1);
        if (nl) stA(0, 1, k2);
        SBAR();
        __builtin_amdgcn_s_setprio(1);
        mma_quad<1, 1>(acc, afr, b1r);
        __builtin_amdgcn_s_setprio(0);
        SBAR();
        // P7: quad(0,1) buf1
        ld_ah(sA1, aOff, afr, pc0, pc1);
        if (nl) stB(1, 0, k3);
        SBAR();
        __builtin_amdgcn_s_setprio(1);
        mma_quad<0, 1>(acc, afr, b1r);
        __builtin_amdgcn_s_setprio(0);
        SBAR();
        // P8: quad(0,0) buf1 | K-tile boundary wait
        if (nl) stB(1, 1, k3);
        SBAR();
        __builtin_amdgcn_s_setprio(1);
        mma_quad<0, 0>(acc, afr, b0r);
        __builtin_amdgcn_s_setprio(0);
        if (nl) { asm volatile("s_waitcnt vmcnt(4)" ::: "memory"); }
        SBAR();
    }

    // ---- fused relu + W3 epilogue: 4 slab passes over Cs[64][260] f32 ----
    float* Cs = (float*)smem;
    const int drow = tid >> 3;            // 0..63
    const int cls = (tid & 7) >> 1;       // 0..3
    const int hf = tid & 1;               // col half
    const float* wrow = &w3s[cls * 260 + hf * 128];
    __syncthreads();
#pragma unroll
    for (int s = 0; s < 4; ++s) {
        if (wM == (s >> 1)) {
            const int mb = (s & 1) * 4;
#pragma unroll
            for (int mi = 0; mi < 4; ++mi)
#pragma unroll
                for (int ni = 0; ni < 4; ++ni) {
                    f32x4 v = acc[mb + mi][ni];
                    const int cbase = (mi * 16 + kq * 4) * 260 + wN * 64 + ni * 16 + l15;
#pragma unroll
                    for (int r = 0; r < 4; ++r)
                        Cs[cbase + r * 260] = fmaxf(v[r] + bias4[ni], 0.f);
                }
        }
        __syncthreads();
        {
            const float* crow = &Cs[drow * 260 + hf * 128];
            float p = 0.f;
#pragma unroll
            for (int ch = 0; ch < 64; ++ch) {
                f32x2 cv = *(const f32x2*)(crow + ch * 2);
                f32x2 wv2 = *(const f32x2*)(wrow + ch * 2);
                p += cv.x * wv2.x + cv.y * wv2.y;
            }
            p += __shfl_xor(p, 1);
            if (hf == 0)
                atomicAdd(&outf[(size_t)(m0 + s * 64 + drow) * 4 + cls], p);
        }
        __syncthreads();
    }
}

// -------------------------------------------------------------- launch ----
extern "C" void kernel_launch(void* const* d_in, const int* in_sizes, int n_in,
                              void* d_out, int out_size, void* d_ws, size_t ws_size,
                              hipStream_t stream) {
    const float* x = (const float*)d_in[0];
    LstmW w;
    for (int l = 0; l < 4; ++l) {
        w.wih[l] = (const float*)d_in[1 + 4 * l];
        w.whh[l] = (const float*)d_in[2 + 4 * l];
        w.bih[l] = (const float*)d_in[3 + 4 * l];
        w.bhh[l] = (const float*)d_in[4 + 4 * l];
    }
    const float* Wd1 = (const float*)d_in[17];
    const float* bd1 = (const float*)d_in[18];
    const float* Wd2 = (const float*)d_in[19];
    const float* bd2 = (const float*)d_in[20];
    const float* Wd3 = (const float*)d_in[21];
    const float* bd3 = (const float*)d_in[22];
    float* out = (float*)d_out;

    ushort* Y   = (ushort*)d_ws;
    ushort* H1  = (ushort*)((char*)d_ws + 6291456);
    ushort* W1b = (ushort*)((char*)d_ws + 39845888);
    ushort* W2b = (ushort*)((char*)d_ws + 40239104);

    pre_kernel<<<1072, 256, 0, stream>>>(x, w, Y, Wd1, Wd2, W1b, W2b, bd3, out);
    gemm1_kernel<<<dim3(128, 8), 256, 0, stream>>>(Y, W1b, bd1, H1, 1024);
    gemm2_kernel<<<512, 512, 0, stream>>>(H1, W2b, bd2, Wd3, out);
}

// Round 2
// 223.281 us; speedup vs baseline: 1.0279x; 1.0279x over previous
//
#include <hip/hip_runtime.h>
#include <hip/hip_bf16.h>

// LSTM_80960133529703: B=16384, T=24, F=7, H=8, L=4; dense 192->1024->2048->4.
// R10: gemm2 = R9's 8-phase 256^2 template, but fragment loads converted to
//      inline-asm ds_read_b128 (opaque to compiler waitcnt insertion), with
//      explicit s_waitcnt lgkmcnt(0) + sched_barrier(0) before each MFMA
//      cluster (rule #18). Theory: hipcc was inserting conservative
//      vmcnt(0) before the tracked C++ ds_reads (global_load_lds writes the
//      same LDS), re-creating the per-phase drain -> 34.7% MfmaUtil == m97
//      plateau. Everything else byte-identical to R9 to isolate the change.
// Schedule (iter i computes K-tiles 2i in buf0, 2i+1 in buf1):
//   stage: P1 b1.Ah0<-2i+1  P2 b1.Ah1<-2i+1  P3 b0.Bh0<-2i+2  P4 b0.Bh1<-2i+2
//          P5 b0.Ah0<-2i+2  P6 b0.Ah1<-2i+2  P7 b1.Bh0<-2i+3  P8 b1.Bh1<-2i+3
//   vmcnt(4)@P4: prev{P7,P8}+{P1,P2} landed  -> P5..P8 reads of buf1 safe
//   vmcnt(4)@P8: {P3..P6} landed             -> next-iter P1..P4 reads of buf0 safe
//   last iter: stages P1/P2 only, vmcnt(0)@P4.
// ws: Y @0 | H1 @6291456 | W1b @39845888 | W2b @40239104
typedef __attribute__((ext_vector_type(4))) float f32x4;
typedef __attribute__((ext_vector_type(16))) float f32x16;
typedef __attribute__((ext_vector_type(2))) float f32x2;
typedef __attribute__((ext_vector_type(8))) short bf16x8;

__device__ __forceinline__ ushort f2bf(float f) {
    union { float f; uint u; } v; v.f = f;
    uint u = v.u;
    return (ushort)((u + 0x7fffu + ((u >> 16) & 1u)) >> 16);   // RNE
}
__device__ __forceinline__ float sigm(float x) {
    return __builtin_amdgcn_rcpf(1.0f + __builtin_amdgcn_exp2f(x * -1.442695040888963f));
}
__device__ __forceinline__ float tanh_(float x) {
    return 2.0f * __builtin_amdgcn_rcpf(1.0f + __builtin_amdgcn_exp2f(x * -2.885390081777927f)) - 1.0f;
}

typedef const __attribute__((address_space(1))) unsigned int ga_u32;
typedef __attribute__((address_space(3))) unsigned int lds_u32;
__device__ __forceinline__ void g2l16(const void* g, void* l) {
    __builtin_amdgcn_global_load_lds((ga_u32*)(unsigned long long)g,
                                     (lds_u32*)(unsigned int)(unsigned long long)l,
                                     16, 0, 0);
}

// ---------------------------------------------------------------- LSTM ----
struct LstmW {
    const float* wih[4];
    const float* whh[4];
    const float* bih[4];
    const float* bhh[4];
};

__device__ __forceinline__ void gates8p(const f32x2 w01[8], const f32x2 w23[8],
                                        const float xv8[8], f32x2& a01, f32x2& a23) {
#pragma unroll
    for (int k = 0; k < 8; ++k) {
        f32x2 xv = {xv8[k], xv8[k]};
        a01 += w01[k] * xv;
        a23 += w23[k] * xv;
    }
}
__device__ __forceinline__ void cellup(f32x2 a01, f32x2 a23, float& h, float& c) {
    c = sigm(a01.y) * c + sigm(a01.x) * tanh_(a23.x);
    h = sigm(a23.y) * tanh_(c);
}
__device__ __forceinline__ void ld8(const float* p, float v[8]) {
    float4 a = *(const float4*)p;
    float4 b = *(const float4*)(p + 4);
    v[0] = a.x; v[1] = a.y; v[2] = a.z; v[3] = a.w;
    v[4] = b.x; v[5] = b.y; v[6] = b.z; v[7] = b.w;
}

// blocks [0,512): LSTM; blocks [512, 512+560): weight cvt fp32->bf16 (+ out init)
__global__ __launch_bounds__(256) void pre_kernel(const float* __restrict__ x, LstmW p,
                                                  ushort* __restrict__ Y,
                                                  const float* __restrict__ W1,
                                                  const float* __restrict__ W2,
                                                  ushort* __restrict__ W1b,
                                                  ushort* __restrict__ W2b,
                                                  const float* __restrict__ b3,
                                                  float* __restrict__ out) {
    __shared__ float xs[32 * 168];
    __shared__ float hb[32 * 200];

    const int tid = threadIdx.x;
    if (blockIdx.x >= 512) {
        const int tg = (blockIdx.x - 512) * 256 + tid;
        if (tg < 16384) {
            float4 bv = {b3[0], b3[1], b3[2], b3[3]};
            ((float4*)out)[tg] = bv;
        }
#pragma unroll
        for (int s = 0; s < 4; ++s) {
            int i = tg + s * 143360;
            const float4* src; ushort4* dst; int off;
            if (i < 49152) { src = (const float4*)W1; dst = (ushort4*)W1b; off = i; }
            else { src = (const float4*)W2; dst = (ushort4*)W2b; off = i - 49152; }
            float4 v = src[off];
            ushort4 r; r.x = f2bf(v.x); r.y = f2bf(v.y); r.z = f2bf(v.z); r.w = f2bf(v.w);
            dst[off] = r;
        }
        return;
    }

    const int e0 = blockIdx.x * 32;
    {
        const float4* s = (const float4*)(x + (size_t)e0 * 168);
        float4* d = (float4*)xs;
        for (int i = tid; i < 1344; i += 256) d[i] = s[i];
    }
    __syncthreads();

    const int el = tid >> 3, j = tid & 7;
    float* hr = hb + el * 200;
    const float* xr = xs + el * 168;

    f32x2 wx01[8], wx23[8], wh01[8], wh23[8], b01, b23;

    // ---- layer 0 (in = 7) ----
    {
        const float* Wih = p.wih[0];
        const float* Whh = p.whh[0];
#pragma unroll
        for (int k = 0; k < 7; ++k) {
            wx01[k] = {Wih[(0 + j) * 7 + k], Wih[(8 + j) * 7 + k]};
            wx23[k] = {Wih[(16 + j) * 7 + k], Wih[(24 + j) * 7 + k]};
        }
#pragma unroll
        for (int k = 0; k < 8; ++k) {
            wh01[k] = {Whh[(0 + j) * 8 + k], Whh[(8 + j) * 8 + k]};
            wh23[k] = {Whh[(16 + j) * 8 + k], Whh[(24 + j) * 8 + k]};
        }
        b01 = {p.bih[0][j] + p.bhh[0][j], p.bih[0][8 + j] + p.bhh[0][8 + j]};
        b23 = {p.bih[0][16 + j] + p.bhh[0][16 + j], p.bih[0][24 + j] + p.bhh[0][24 + j]};

        float h = 0.f, c = 0.f;
        {
            f32x2 a01 = b01, a23 = b23;
#pragma unroll
            for (int k = 0; k < 7; ++k) {
                f32x2 xv = {xr[k], xr[k]};
                a01 += wx01[k] * xv; a23 += wx23[k] * xv;
            }
            cellup(a01, a23, h, c);
            hr[j] = h;
        }
        for (int t = 1; t < 24; ++t) {
            f32x2 a01 = b01, a23 = b23;
#pragma unroll
            for (int k = 0; k < 7; ++k) {
                f32x2 xv = {xr[t * 7 + k], xr[t * 7 + k]};
                a01 += wx01[k] * xv; a23 += wx23[k] * xv;
            }
            float hp[8]; ld8(&hr[(t - 1) * 8], hp);
            gates8p(wh01, wh23, hp, a01, a23);
            cellup(a01, a23, h, c);
            hr[t * 8 + j] = h;
        }
    }

    // ---- layers 1..3 ----
#pragma unroll
    for (int l = 1; l < 4; ++l) {
        const float* Wih = p.wih[l];
        const float* Whh = p.whh[l];
#pragma unroll
        for (int k = 0; k < 8; ++k) {
            wx01[k] = {Wih[(0 + j) * 8 + k], Wih[(8 + j) * 8 + k]};
            wx23[k] = {Wih[(16 + j) * 8 + k], Wih[(24 + j) * 8 + k]};
            wh01[k] = {Whh[(0 + j) * 8 + k], Whh[(8 + j) * 8 + k]};
            wh23[k] = {Whh[(16 + j) * 8 + k], Whh[(24 + j) * 8 + k]};
        }
        b01 = {p.bih[l][j] + p.bhh[l][j], p.bih[l][8 + j] + p.bhh[l][8 + j]};
        b23 = {p.bih[l][16 + j] + p.bhh[l][16 + j], p.bih[l][24 + j] + p.bhh[l][24 + j]};

        float h = 0.f, c = 0.f;
        {
            float xin[8]; ld8(&hr[0], xin);
            f32x2 a01 = b01, a23 = b23;
            gates8p(wx01, wx23, xin, a01, a23);
            cellup(a01, a23, h, c);
            hr[j] = h;
            if (l == 3) Y[((size_t)(e0 + el) * 24) * 8 + j] = f2bf(h);
        }
        for (int t = 1; t < 24; ++t) {
            float xin[8]; ld8(&hr[t * 8], xin);
            float hp[8];  ld8(&hr[(t - 1) * 8], hp);
            f32x2 a01 = b01, a23 = b23;
            gates8p(wx01, wx23, xin, a01, a23);
            gates8p(wh01, wh23, hp, a01, a23);
            cellup(a01, a23, h, c);
            hr[t * 8 + j] = h;
            if (l == 3) Y[((size_t)(e0 + el) * 24 + t) * 8 + j] = f2bf(h);
        }
    }
}

// ------------------------------------------------------- gemm1 (K=192) ----
// Tile 128x128, BK=64, 4 waves; wave tile 64x64 as 2x2 of mfma_32x32x16.
// Unchanged from R8 (K too shallow for the 8-phase pipeline).
template <int KDIM>
__device__ __forceinline__ void gemm_body(const ushort* __restrict__ A,
                                          const ushort* __restrict__ W,
                                          const float* __restrict__ bias,
                                          ushort* __restrict__ Hout, int N) {
    __shared__ alignas(16) ushort smem[16384];
    ushort* As = smem;            // [128][64] swizzled
    ushort* Ws = smem + 8192;

    const int tid = threadIdx.x;
    const int m0 = blockIdx.x * 128;
    const int n0 = blockIdx.y * 128;
    const int lane = tid & 63;
    const int wv = tid >> 6;
    const int wm = (wv & 1) * 64;
    const int wn = (wv >> 1) * 64;
    const int l31 = lane & 31;
    const int kh = lane >> 5;

    // staging: per wave, 4 calls/tensor; call c: rows wv*32 + c*8 + lrow
    const int lrow = lane >> 3;
    const int lchunk = (lane & 7) ^ lrow;          // XOR swizzle at source
    const ushort* Ag = A + (size_t)(m0 + wv * 32 + lrow) * KDIM + lchunk * 8;
    const ushort* Wg = W + (size_t)(n0 + wv * 32 + lrow) * KDIM + lchunk * 8;
    ushort* Ald = As + wv * 2048;
    ushort* Wld = Ws + wv * 2048;

    const int r7 = l31 & 7;
    const int arow0 = (wm + l31) * 64;        // mi=0; mi=1 adds 32*64
    const int brow0 = (wn + l31) * 64;

    f32x16 acc[2][2];
#pragma unroll
    for (int mi = 0; mi < 2; ++mi)
#pragma unroll
        for (int ni = 0; ni < 2; ++ni)
#pragma unroll
            for (int r = 0; r < 16; ++r) acc[mi][ni][r] = 0.f;

    for (int k0 = 0; k0 < KDIM; k0 += 64) {
#pragma unroll
        for (int c = 0; c < 4; ++c)
            g2l16(Ag + (size_t)c * 8 * KDIM + k0, Ald + c * 512);
#pragma unroll
        for (int c = 0; c < 4; ++c)
            g2l16(Wg + (size_t)c * 8 * KDIM + k0, Wld + c * 512);
        __syncthreads();

#pragma unroll
        for (int ks = 0; ks < 4; ++ks) {
            const int ck = ((ks * 2 + kh) ^ r7) * 8;
            bf16x8 afr[2], bfr[2];
#pragma unroll
            for (int mi = 0; mi < 2; ++mi)
                afr[mi] = *(const bf16x8*)&As[arow0 + mi * 2048 + ck];
#pragma unroll
            for (int ni = 0; ni < 2; ++ni)
                bfr[ni] = *(const bf16x8*)&Ws[brow0 + ni * 2048 + ck];
#pragma unroll
            for (int mi = 0; mi < 2; ++mi)
#pragma unroll
                for (int ni = 0; ni < 2; ++ni)
                    acc[mi][ni] = __builtin_amdgcn_mfma_f32_32x32x16_bf16(afr[mi], bfr[ni],
                                                                         acc[mi][ni], 0, 0, 0);
        }
        __syncthreads();
    }

#pragma unroll
    for (int ni = 0; ni < 2; ++ni) {
        const int col = n0 + wn + ni * 32 + l31;
        const float b = bias[col];
#pragma unroll
        for (int mi = 0; mi < 2; ++mi)
#pragma unroll
            for (int r = 0; r < 16; ++r) {
                const int row = m0 + wm + mi * 32 + (r & 3) + 8 * (r >> 2) + 4 * kh;
                Hout[(size_t)row * N + col] = f2bf(fmaxf(acc[mi][ni][r] + b, 0.f));
            }
    }
}

__global__ __launch_bounds__(256, 4) void gemm1_kernel(const ushort* __restrict__ A,
                                                       const ushort* __restrict__ W,
                                                       const float* __restrict__ bias,
                                                       ushort* __restrict__ Hout, int N) {
    gemm_body<192>(A, W, bias, Hout, N);
}

// ---------------------------------------------- gemm2: 256^2 8-phase -----
// Opaque LDS fragment read: compiler cannot attach vmcnt/lgkmcnt waits to it.
template <int OFFB>
__device__ __forceinline__ bf16x8 dsr(unsigned a) {
    bf16x8 r;
    asm volatile("ds_read_b128 %0, %1 offset:%2"
                 : "=v"(r) : "v"(a), "i"(OFFB));
    return r;
}
// A-half: 8 reads (4 frags x {pc0,pc1}); B-half: 4 reads.
template <int B>
__device__ __forceinline__ void ld_ah_asm(unsigned p0, unsigned p1, bf16x8 fr[8]) {
    fr[0] = dsr<B + 0>(p0);    fr[1] = dsr<B + 0>(p1);
    fr[2] = dsr<B + 2048>(p0); fr[3] = dsr<B + 2048>(p1);
    fr[4] = dsr<B + 4096>(p0); fr[5] = dsr<B + 4096>(p1);
    fr[6] = dsr<B + 6144>(p0); fr[7] = dsr<B + 6144>(p1);
}
template <int B>
__device__ __forceinline__ void ld_bh_asm(unsigned p0, unsigned p1, bf16x8 fr[4]) {
    fr[0] = dsr<B + 0>(p0);    fr[1] = dsr<B + 0>(p1);
    fr[2] = dsr<B + 2048>(p0); fr[3] = dsr<B + 2048>(p1);
}
// one C-quadrant (4 mi x 2 ni) over the full K=64 tile (2 ks)
template <int QA, int QB>
__device__ __forceinline__ void mma_quad(f32x4 acc[8][4], const bf16x8 afr[8],
                                         const bf16x8 bfr[4]) {
#pragma unroll
    for (int ks = 0; ks < 2; ++ks)
#pragma unroll
        for (int mi = 0; mi < 4; ++mi)
#pragma unroll
            for (int ni = 0; ni < 2; ++ni)
                acc[QA * 4 + mi][QB * 2 + ni] = __builtin_amdgcn_mfma_f32_16x16x32_bf16(
                    afr[mi * 2 + ks], bfr[ni * 2 + ks], acc[QA * 4 + mi][QB * 2 + ni],
                    0, 0, 0);
}

#define SBAR() __builtin_amdgcn_s_barrier()
// barrier -> wait for this phase's ds_reads -> pin MFMAs below (rule #18)
#define MMA_GATE() do { SBAR(); \
    asm volatile("s_waitcnt lgkmcnt(0)"); \
    __builtin_amdgcn_sched_barrier(0); } while (0)
#define CLUSTER_END() do { __builtin_amdgcn_s_setprio(0); \
    __builtin_amdgcn_sched_barrier(0); } while (0)

__global__ __launch_bounds__(512) void gemm2_kernel(const ushort* __restrict__ A,
                                                    const ushort* __restrict__ W,
                                                    const float* __restrict__ bias,
                                                    const float* __restrict__ W3,
                                                    float* __restrict__ outf) {
    // LDS: 2 K-tile double buffer, [256 rows][64 k] bf16 per tensor per buf.
    // A0 @0, B0 @16384, A1 @32768, B1 @49152 (ushort offsets). 128 KiB.
    __shared__ alignas(16) ushort smem[65536];
    __shared__ alignas(16) float w3s[1040];   // W3[4][256] at pitch 260

    const int tid = threadIdx.x;
    // bijective XCD swizzle (512 % 8 == 0): each XCD gets 8 consecutive
    // bm panels x all 8 bn -> A panel + B slab L2-resident per XCD.
    const int wg = ((int)blockIdx.x & 7) * 64 + ((int)blockIdx.x >> 3);
    const int m0 = (wg >> 3) << 8;
    const int n0 = (wg & 7) << 8;

    const int lane = tid & 63;
    const int wv = tid >> 6;

    // ---- staging addressing (pre-swizzled global source, linear LDS dest)
    const int lrow = tid >> 3;                         // 0..63 rows per call
    const int lc8 = ((tid & 7) ^ (lrow & 7)) << 3;     // swizzled k-chunk
    const ushort* Ag = A + (size_t)(m0 + lrow) * 1024 + lc8;
    const ushort* Bg = W + (size_t)(n0 + lrow) * 1024 + lc8;
    ushort* const sA0 = smem;
    ushort* const sB0 = smem + 16384;
    ushort* const sA1 = smem + 32768;
    ushort* const sB1 = smem + 49152;
    const int srow64 = (wv << 3) * 64;                 // wave's LDS row base

    // ---- frag addressing: phys chunk = logical ^ (row&7); byte addrs for asm
    const int l15 = lane & 15, kq = lane >> 4, r7 = l15 & 7;
    const int wM = wv >> 2, wN = wv & 3;               // 2M x 4N waves
    const unsigned sbase = (unsigned)(unsigned long long)&smem[0];
    const unsigned pc0B = (unsigned)((kq ^ r7) << 4);
    const unsigned pc1B = pc0B ^ 64u;                  // chunk ^= 4
    const unsigned aRowB = (unsigned)((wM * 128 + l15) * 128);
    const unsigned bRowB = (unsigned)((wN * 64 + l15) * 128);
    const unsigned aA0p0 = sbase + aRowB + pc0B;
    const unsigned aA0p1 = sbase + aRowB + pc1B;
    const unsigned aA1p0 = aA0p0 + 65536u;
    const unsigned aA1p1 = aA0p1 + 65536u;
    const unsigned bB0p0 = sbase + 32768u + bRowB + pc0B;
    const unsigned bB0p1 = sbase + 32768u + bRowB + pc1B;
    const unsigned bB1p0 = bB0p0 + 65536u;
    const unsigned bB1p1 = bB0p1 + 65536u;

    auto stA = [&](int buf, int h, int kt) {           // stage A half-tile
        ushort* b = buf ? sA1 : sA0;
#pragma unroll
        for (int c = 0; c < 2; ++c)
            g2l16(Ag + (size_t)(h * 128 + c * 64) * 1024 + kt * 64,
                  b + (h * 128 + c * 64) * 64 + srow64);
    };
    auto stB = [&](int buf, int h, int kt) {           // stage B half-tile
        ushort* b = buf ? sB1 : sB0;
#pragma unroll
        for (int c = 0; c < 2; ++c)
            g2l16(Bg + (size_t)(h * 128 + c * 64) * 1024 + kt * 64,
                  b + (h * 128 + c * 64) * 64 + srow64);
    };

    f32x4 acc[8][4];
#pragma unroll
    for (int i = 0; i < 8; ++i)
#pragma unroll
        for (int j = 0; j < 4; ++j)
#pragma unroll
            for (int r = 0; r < 4; ++r) acc[i][j][r] = 0.f;

    // W3 -> LDS + bias -> regs (issued before staging; prologue vmcnt(0)
    // drains them so in-loop vmcnt counts are staging-only).
#pragma unroll
    for (int i = 0; i < 2; ++i) {
        int idx = tid + i * 512;
        w3s[(idx >> 8) * 260 + (idx & 255)] = W3[(size_t)(idx >> 8) * 2048 + n0 + (idx & 255)];
    }
    float bias4[4];
#pragma unroll
    for (int ni = 0; ni < 4; ++ni) bias4[ni] = bias[n0 + wN * 64 + ni * 16 + l15];

    // prologue: buf0 (kt 0) full + buf1.B (kt 1); buf1.A comes from P1/P2.
    stA(0, 0, 0); stB(0, 0, 0); stB(0, 1, 0); stA(0, 1, 0);
    stB(1, 0, 1); stB(1, 1, 1);
    asm volatile("s_waitcnt vmcnt(0)" ::: "memory");
    SBAR();

    bf16x8 afr[8], b0r[4], b1r[4];
#pragma unroll 1
    for (int it = 0; it < 8; ++it) {
        const int k1 = 2 * it + 1, k2 = 2 * it + 2, k3 = 2 * it + 3;
        const bool nl = (it < 7);
        // P1: quad(0,0) buf0
        ld_ah_asm<0>(aA0p0, aA0p1, afr);
        ld_bh_asm<0>(bB0p0, bB0p1, b0r);
        stA(1, 0, k1);
        MMA_GATE();
        __builtin_amdgcn_s_setprio(1);
        mma_quad<0, 0>(acc, afr, b0r);
        CLUSTER_END();
        SBAR();
        // P2: quad(0,1) buf0
        ld_bh_asm<4096>(bB0p0, bB0p1, b1r);
        stA(1, 1, k1);
        MMA_GATE();
        __builtin_amdgcn_s_setprio(1);
        mma_quad<0, 1>(acc, afr, b1r);
        CLUSTER_END();
        SBAR();
        // P3: quad(1,1) buf0
        ld_ah_asm<8192>(aA0p0, aA0p1, afr);
        if (nl) stB(0, 0, k2);
        MMA_GATE();
        __builtin_amdgcn_s_setprio(1);
        mma_quad<1, 1>(acc, afr, b1r);
        CLUSTER_END();
        SBAR();
        // P4: quad(1,0) buf0 | K-tile boundary wait
        if (nl) stB(0, 1, k2);
        MMA_GATE();
        __builtin_amdgcn_s_setprio(1);
        mma_quad<1, 0>(acc, afr, b0r);
        CLUSTER_END();
        if (nl) { asm volatile("s_waitcnt vmcnt(4)" ::: "memory"); }
        else    { asm volatile("s_waitcnt vmcnt(0)" ::: "memory"); }
        SBAR();
        // P5: quad(1,0) buf1
        ld_ah_asm<8192>(aA1p0, aA1p1, afr);
        ld_bh_asm<0>(bB1p0, bB1p1, b0r);
        if (nl) stA(0, 0, k2);
        MMA_GATE();
        __builtin_amdgcn_s_setprio(1);
        mma_quad<1, 0>(acc, afr, b0r);
        CLUSTER_END();
        SBAR();
        // P6: quad(1,1) buf1
        ld_bh_asm<4096>(bB1p0, bB1p1, b1r);
        if (nl) stA(0, 1, k2);
        MMA_GATE();
        __builtin_amdgcn_s_setprio(1);
        mma_quad<1, 1>(acc, afr, b1r);
        CLUSTER_END();
        SBAR();
        // P7: quad(0,1) buf1
        ld_ah_asm<0>(aA1p0, aA1p1, afr);
        if (nl) stB(1, 0, k3);
        MMA_GATE();
        __builtin_amdgcn_s_setprio(1);
        mma_quad<0, 1>(acc, afr, b1r);
        CLUSTER_END();
        SBAR();
        // P8: quad(0,0) buf1 | K-tile boundary wait
        if (nl) stB(1, 1, k3);
        MMA_GATE();
        __builtin_amdgcn_s_setprio(1);
        mma_quad<0, 0>(acc, afr, b0r);
        CLUSTER_END();
        if (nl) { asm volatile("s_waitcnt vmcnt(4)" ::: "memory"); }
        SBAR();
    }

    // ---- fused relu + W3 epilogue: 4 slab passes over Cs[64][260] f32 ----
    float* Cs = (float*)smem;
    const int drow = tid >> 3;            // 0..63
    const int cls = (tid & 7) >> 1;       // 0..3
    const int hf = tid & 1;               // col half
    const float* wrow = &w3s[cls * 260 + hf * 128];
    __syncthreads();
#pragma unroll
    for (int s = 0; s < 4; ++s) {
        if (wM == (s >> 1)) {
            const int mb = (s & 1) * 4;
#pragma unroll
            for (int mi = 0; mi < 4; ++mi)
#pragma unroll
                for (int ni = 0; ni < 4; ++ni) {
                    f32x4 v = acc[mb + mi][ni];
                    const int cbase = (mi * 16 + kq * 4) * 260 + wN * 64 + ni * 16 + l15;
#pragma unroll
                    for (int r = 0; r < 4; ++r)
                        Cs[cbase + r * 260] = fmaxf(v[r] + bias4[ni], 0.f);
                }
        }
        __syncthreads();
        {
            const float* crow = &Cs[drow * 260 + hf * 128];
            float p = 0.f;
#pragma unroll
            for (int ch = 0; ch < 64; ++ch) {
                f32x2 cv = *(const f32x2*)(crow + ch * 2);
                f32x2 wv2 = *(const f32x2*)(wrow + ch * 2);
                p += cv.x * wv2.x + cv.y * wv2.y;
            }
            p += __shfl_xor(p, 1);
            if (hf == 0)
                atomicAdd(&outf[(size_t)(m0 + s * 64 + drow) * 4 + cls], p);
        }
        __syncthreads();
    }
}

// -------------------------------------------------------------- launch ----
extern "C" void kernel_launch(void* const* d_in, const int* in_sizes, int n_in,
                              void* d_out, int out_size, void* d_ws, size_t ws_size,
                              hipStream_t stream) {
    const float* x = (const float*)d_in[0];
    LstmW w;
    for (int l = 0; l < 4; ++l) {
        w.wih[l] = (const float*)d_in[1 + 4 * l];
        w.whh[l] = (const float*)d_in[2 + 4 * l];
        w.bih[l] = (const float*)d_in[3 + 4 * l];
        w.bhh[l] = (const float*)d_in[4 + 4 * l];
    }
    const float* Wd1 = (const float*)d_in[17];
    const float* bd1 = (const float*)d_in[18];
    const float* Wd2 = (const float*)d_in[19];
    const float* bd2 = (const float*)d_in[20];
    const float* Wd3 = (const float*)d_in[21];
    const float* bd3 = (const float*)d_in[22];
    float* out = (float*)d_out;

    ushort* Y   = (ushort*)d_ws;
    ushort* H1  = (ushort*)((char*)d_ws + 6291456);
    ushort* W1b = (ushort*)((char*)d_ws + 39845888);
    ushort* W2b = (ushort*)((char*)d_ws + 40239104);

    pre_kernel<<<1072, 256, 0, stream>>>(x, w, Y, Wd1, Wd2, W1b, W2b, bd3, out);
    gemm1_kernel<<<dim3(128, 8), 256, 0, stream>>>(Y, W1b, bd1, H1, 1024);
    gemm2_kernel<<<512, 512, 0, stream>>>(H1, W2b, bd2, Wd3, out);
}

// Round 3
// 210.020 us; speedup vs baseline: 1.0928x; 1.0631x over previous
//
#include <hip/hip_runtime.h>
#include <hip/hip_bf16.h>

// LSTM_80960133529703: B=16384, T=24, F=7, H=8, L=4; dense 192->1024->2048->4.
// R11: gemm2 = 8-phase 256^2 template with HALF-PHASE-AHEAD register
//      prefetch. R10's per-phase {reads -> lgkmcnt(0) -> 16 MFMA} serialized
//      the LDS pipe against the MFMA pipe (per-iter wall ~= t_lds + t_mfma,
//      11.9K cyc vs ~5K each). Now each phase = two 8-MFMA sub-clusters;
//      reads for sub X issue before sub X-1's MFMAs, gated by COUNTED
//      lgkmcnt(N). One barrier per phase (was 2). Same registers (afr/b0r/
//      b1r, sub-granular overwrite - liveness audited), same staging/swizzle/
//      vmcnt(2)@P4,P8 ledger, same epilogue. gemm1/pre_kernel unchanged.
// lgkm ledger (steady, per wave): P8tail+6 | P1h+6 G6 | P1t+2 G2 | P2h+2 G2
//   | P2t+4 G4 | P3h+4 G4 G0 | P4t+6 | P5h+6 G6 | P5t+2 G2 | P6h+2 G2
//   | P6t+4 G4 | P7h+4 G4 G0 | P8t+6 (next iter)
// vmcnt ledger: @P4head outstanding {P7p,P8p,P1,P2,P3}=10 -> vmcnt(2) lands
//   buf1 (A from P1/P2, B from P7p/P8p); @P8head {P3..P7}=10 -> vmcnt(2)
//   lands buf0 k2 (P3..P6). it7: P4 vmcnt(0), stages P3..P8 + P8tail skipped.
// ws: Y @0 | H1 @6291456 | W1b @39845888 | W2b @40239104
typedef __attribute__((ext_vector_type(4))) float f32x4;
typedef __attribute__((ext_vector_type(16))) float f32x16;
typedef __attribute__((ext_vector_type(2))) float f32x2;
typedef __attribute__((ext_vector_type(8))) short bf16x8;

__device__ __forceinline__ ushort f2bf(float f) {
    union { float f; uint u; } v; v.f = f;
    uint u = v.u;
    return (ushort)((u + 0x7fffu + ((u >> 16) & 1u)) >> 16);   // RNE
}
__device__ __forceinline__ float sigm(float x) {
    return __builtin_amdgcn_rcpf(1.0f + __builtin_amdgcn_exp2f(x * -1.442695040888963f));
}
__device__ __forceinline__ float tanh_(float x) {
    return 2.0f * __builtin_amdgcn_rcpf(1.0f + __builtin_amdgcn_exp2f(x * -2.885390081777927f)) - 1.0f;
}

typedef const __attribute__((address_space(1))) unsigned int ga_u32;
typedef __attribute__((address_space(3))) unsigned int lds_u32;
__device__ __forceinline__ void g2l16(const void* g, void* l) {
    __builtin_amdgcn_global_load_lds((ga_u32*)(unsigned long long)g,
                                     (lds_u32*)(unsigned int)(unsigned long long)l,
                                     16, 0, 0);
}

// ---------------------------------------------------------------- LSTM ----
struct LstmW {
    const float* wih[4];
    const float* whh[4];
    const float* bih[4];
    const float* bhh[4];
};

__device__ __forceinline__ void gates8p(const f32x2 w01[8], const f32x2 w23[8],
                                        const float xv8[8], f32x2& a01, f32x2& a23) {
#pragma unroll
    for (int k = 0; k < 8; ++k) {
        f32x2 xv = {xv8[k], xv8[k]};
        a01 += w01[k] * xv;
        a23 += w23[k] * xv;
    }
}
__device__ __forceinline__ void cellup(f32x2 a01, f32x2 a23, float& h, float& c) {
    c = sigm(a01.y) * c + sigm(a01.x) * tanh_(a23.x);
    h = sigm(a23.y) * tanh_(c);
}
__device__ __forceinline__ void ld8(const float* p, float v[8]) {
    float4 a = *(const float4*)p;
    float4 b = *(const float4*)(p + 4);
    v[0] = a.x; v[1] = a.y; v[2] = a.z; v[3] = a.w;
    v[4] = b.x; v[5] = b.y; v[6] = b.z; v[7] = b.w;
}

// blocks [0,512): LSTM; blocks [512, 512+560): weight cvt fp32->bf16 (+ out init)
__global__ __launch_bounds__(256) void pre_kernel(const float* __restrict__ x, LstmW p,
                                                  ushort* __restrict__ Y,
                                                  const float* __restrict__ W1,
                                                  const float* __restrict__ W2,
                                                  ushort* __restrict__ W1b,
                                                  ushort* __restrict__ W2b,
                                                  const float* __restrict__ b3,
                                                  float* __restrict__ out) {
    __shared__ float xs[32 * 168];
    __shared__ float hb[32 * 200];

    const int tid = threadIdx.x;
    if (blockIdx.x >= 512) {
        const int tg = (blockIdx.x - 512) * 256 + tid;
        if (tg < 16384) {
            float4 bv = {b3[0], b3[1], b3[2], b3[3]};
            ((float4*)out)[tg] = bv;
        }
#pragma unroll
        for (int s = 0; s < 4; ++s) {
            int i = tg + s * 143360;
            const float4* src; ushort4* dst; int off;
            if (i < 49152) { src = (const float4*)W1; dst = (ushort4*)W1b; off = i; }
            else { src = (const float4*)W2; dst = (ushort4*)W2b; off = i - 49152; }
            float4 v = src[off];
            ushort4 r; r.x = f2bf(v.x); r.y = f2bf(v.y); r.z = f2bf(v.z); r.w = f2bf(v.w);
            dst[off] = r;
        }
        return;
    }

    const int e0 = blockIdx.x * 32;
    {
        const float4* s = (const float4*)(x + (size_t)e0 * 168);
        float4* d = (float4*)xs;
        for (int i = tid; i < 1344; i += 256) d[i] = s[i];
    }
    __syncthreads();

    const int el = tid >> 3, j = tid & 7;
    float* hr = hb + el * 200;
    const float* xr = xs + el * 168;

    f32x2 wx01[8], wx23[8], wh01[8], wh23[8], b01, b23;

    // ---- layer 0 (in = 7) ----
    {
        const float* Wih = p.wih[0];
        const float* Whh = p.whh[0];
#pragma unroll
        for (int k = 0; k < 7; ++k) {
            wx01[k] = {Wih[(0 + j) * 7 + k], Wih[(8 + j) * 7 + k]};
            wx23[k] = {Wih[(16 + j) * 7 + k], Wih[(24 + j) * 7 + k]};
        }
#pragma unroll
        for (int k = 0; k < 8; ++k) {
            wh01[k] = {Whh[(0 + j) * 8 + k], Whh[(8 + j) * 8 + k]};
            wh23[k] = {Whh[(16 + j) * 8 + k], Whh[(24 + j) * 8 + k]};
        }
        b01 = {p.bih[0][j] + p.bhh[0][j], p.bih[0][8 + j] + p.bhh[0][8 + j]};
        b23 = {p.bih[0][16 + j] + p.bhh[0][16 + j], p.bih[0][24 + j] + p.bhh[0][24 + j]};

        float h = 0.f, c = 0.f;
        {
            f32x2 a01 = b01, a23 = b23;
#pragma unroll
            for (int k = 0; k < 7; ++k) {
                f32x2 xv = {xr[k], xr[k]};
                a01 += wx01[k] * xv; a23 += wx23[k] * xv;
            }
            cellup(a01, a23, h, c);
            hr[j] = h;
        }
        for (int t = 1; t < 24; ++t) {
            f32x2 a01 = b01, a23 = b23;
#pragma unroll
            for (int k = 0; k < 7; ++k) {
                f32x2 xv = {xr[t * 7 + k], xr[t * 7 + k]};
                a01 += wx01[k] * xv; a23 += wx23[k] * xv;
            }
            float hp[8]; ld8(&hr[(t - 1) * 8], hp);
            gates8p(wh01, wh23, hp, a01, a23);
            cellup(a01, a23, h, c);
            hr[t * 8 + j] = h;
        }
    }

    // ---- layers 1..3 ----
#pragma unroll
    for (int l = 1; l < 4; ++l) {
        const float* Wih = p.wih[l];
        const float* Whh = p.whh[l];
#pragma unroll
        for (int k = 0; k < 8; ++k) {
            wx01[k] = {Wih[(0 + j) * 8 + k], Wih[(8 + j) * 8 + k]};
            wx23[k] = {Wih[(16 + j) * 8 + k], Wih[(24 + j) * 8 + k]};
            wh01[k] = {Whh[(0 + j) * 8 + k], Whh[(8 + j) * 8 + k]};
            wh23[k] = {Whh[(16 + j) * 8 + k], Whh[(24 + j) * 8 + k]};
        }
        b01 = {p.bih[l][j] + p.bhh[l][j], p.bih[l][8 + j] + p.bhh[l][8 + j]};
        b23 = {p.bih[l][16 + j] + p.bhh[l][16 + j], p.bih[l][24 + j] + p.bhh[l][24 + j]};

        float h = 0.f, c = 0.f;
        {
            float xin[8]; ld8(&hr[0], xin);
            f32x2 a01 = b01, a23 = b23;
            gates8p(wx01, wx23, xin, a01, a23);
            cellup(a01, a23, h, c);
            hr[j] = h;
            if (l == 3) Y[((size_t)(e0 + el) * 24) * 8 + j] = f2bf(h);
        }
        for (int t = 1; t < 24; ++t) {
            float xin[8]; ld8(&hr[t * 8], xin);
            float hp[8];  ld8(&hr[(t - 1) * 8], hp);
            f32x2 a01 = b01, a23 = b23;
            gates8p(wx01, wx23, xin, a01, a23);
            gates8p(wh01, wh23, hp, a01, a23);
            cellup(a01, a23, h, c);
            hr[t * 8 + j] = h;
            if (l == 3) Y[((size_t)(e0 + el) * 24 + t) * 8 + j] = f2bf(h);
        }
    }
}

// ------------------------------------------------------- gemm1 (K=192) ----
// Tile 128x128, BK=64, 4 waves; wave tile 64x64 as 2x2 of mfma_32x32x16.
template <int KDIM>
__device__ __forceinline__ void gemm_body(const ushort* __restrict__ A,
                                          const ushort* __restrict__ W,
                                          const float* __restrict__ bias,
                                          ushort* __restrict__ Hout, int N) {
    __shared__ alignas(16) ushort smem[16384];
    ushort* As = smem;            // [128][64] swizzled
    ushort* Ws = smem + 8192;

    const int tid = threadIdx.x;
    const int m0 = blockIdx.x * 128;
    const int n0 = blockIdx.y * 128;
    const int lane = tid & 63;
    const int wv = tid >> 6;
    const int wm = (wv & 1) * 64;
    const int wn = (wv >> 1) * 64;
    const int l31 = lane & 31;
    const int kh = lane >> 5;

    // staging: per wave, 4 calls/tensor; call c: rows wv*32 + c*8 + lrow
    const int lrow = lane >> 3;
    const int lchunk = (lane & 7) ^ lrow;          // XOR swizzle at source
    const ushort* Ag = A + (size_t)(m0 + wv * 32 + lrow) * KDIM + lchunk * 8;
    const ushort* Wg = W + (size_t)(n0 + wv * 32 + lrow) * KDIM + lchunk * 8;
    ushort* Ald = As + wv * 2048;
    ushort* Wld = Ws + wv * 2048;

    const int r7 = l31 & 7;
    const int arow0 = (wm + l31) * 64;        // mi=0; mi=1 adds 32*64
    const int brow0 = (wn + l31) * 64;

    f32x16 acc[2][2];
#pragma unroll
    for (int mi = 0; mi < 2; ++mi)
#pragma unroll
        for (int ni = 0; ni < 2; ++ni)
#pragma unroll
            for (int r = 0; r < 16; ++r) acc[mi][ni][r] = 0.f;

    for (int k0 = 0; k0 < KDIM; k0 += 64) {
#pragma unroll
        for (int c = 0; c < 4; ++c)
            g2l16(Ag + (size_t)c * 8 * KDIM + k0, Ald + c * 512);
#pragma unroll
        for (int c = 0; c < 4; ++c)
            g2l16(Wg + (size_t)c * 8 * KDIM + k0, Wld + c * 512);
        __syncthreads();

#pragma unroll
        for (int ks = 0; ks < 4; ++ks) {
            const int ck = ((ks * 2 + kh) ^ r7) * 8;
            bf16x8 afr[2], bfr[2];
#pragma unroll
            for (int mi = 0; mi < 2; ++mi)
                afr[mi] = *(const bf16x8*)&As[arow0 + mi * 2048 + ck];
#pragma unroll
            for (int ni = 0; ni < 2; ++ni)
                bfr[ni] = *(const bf16x8*)&Ws[brow0 + ni * 2048 + ck];
#pragma unroll
            for (int mi = 0; mi < 2; ++mi)
#pragma unroll
                for (int ni = 0; ni < 2; ++ni)
                    acc[mi][ni] = __builtin_amdgcn_mfma_f32_32x32x16_bf16(afr[mi], bfr[ni],
                                                                         acc[mi][ni], 0, 0, 0);
        }
        __syncthreads();
    }

#pragma unroll
    for (int ni = 0; ni < 2; ++ni) {
        const int col = n0 + wn + ni * 32 + l31;
        const float b = bias[col];
#pragma unroll
        for (int mi = 0; mi < 2; ++mi)
#pragma unroll
            for (int r = 0; r < 16; ++r) {
                const int row = m0 + wm + mi * 32 + (r & 3) + 8 * (r >> 2) + 4 * kh;
                Hout[(size_t)row * N + col] = f2bf(fmaxf(acc[mi][ni][r] + b, 0.f));
            }
    }
}

__global__ __launch_bounds__(256, 4) void gemm1_kernel(const ushort* __restrict__ A,
                                                       const ushort* __restrict__ W,
                                                       const float* __restrict__ bias,
                                                       ushort* __restrict__ Hout, int N) {
    gemm_body<192>(A, W, bias, Hout, N);
}

// ---------------------------------------------- gemm2: 256^2 8-phase -----
template <int OFFB>
__device__ __forceinline__ bf16x8 dsr(unsigned a) {
    bf16x8 r;
    asm volatile("ds_read_b128 %0, %1 offset:%2"
                 : "=v"(r) : "v"(a), "i"(OFFB));
    return r;
}
// one 8-MFMA sub-cluster: quad (QA,QB), k-slice KS
template <int QA, int QB, int KS>
__device__ __forceinline__ void mma_sub(f32x4 acc[8][4], const bf16x8 afr[8],
                                        const bf16x8 br[4]) {
#pragma unroll
    for (int mi = 0; mi < 4; ++mi)
#pragma unroll
        for (int ni = 0; ni < 2; ++ni)
            acc[QA * 4 + mi][QB * 2 + ni] = __builtin_amdgcn_mfma_f32_16x16x32_bf16(
                afr[mi * 2 + KS], br[ni * 2 + KS], acc[QA * 4 + mi][QB * 2 + ni],
                0, 0, 0);
}

#define SBAR()  __builtin_amdgcn_s_barrier()
#define SCHED0() __builtin_amdgcn_sched_barrier(0)
#define LGKM(N) do { asm volatile("s_waitcnt lgkmcnt(" #N ")"); SCHED0(); } while (0)
#define VMC(N)  do { asm volatile("s_waitcnt vmcnt(" #N ")" ::: "memory"); } while (0)
#define PRIO1() __builtin_amdgcn_s_setprio(1)
#define PRIO0() do { __builtin_amdgcn_s_setprio(0); SCHED0(); } while (0)

__global__ __launch_bounds__(512) void gemm2_kernel(const ushort* __restrict__ A,
                                                    const ushort* __restrict__ W,
                                                    const float* __restrict__ bias,
                                                    const float* __restrict__ W3,
                                                    float* __restrict__ outf) {
    // LDS: 2 K-tile double buffer, [256 rows][64 k] bf16 per tensor per buf.
    // A0 @0, B0 @32768, A1 @65536, B1 @98304 (byte offsets). 128 KiB.
    __shared__ alignas(16) ushort smem[65536];
    __shared__ alignas(16) float w3s[1040];   // W3[4][256] at pitch 260

    const int tid = threadIdx.x;
    // bijective XCD swizzle (512 % 8 == 0)
    const int wg = ((int)blockIdx.x & 7) * 64 + ((int)blockIdx.x >> 3);
    const int m0 = (wg >> 3) << 8;
    const int n0 = (wg & 7) << 8;

    const int lane = tid & 63;
    const int wv = tid >> 6;

    // ---- staging addressing (pre-swizzled global source, linear LDS dest)
    const int lrow = tid >> 3;                         // 0..63 rows per call
    const int lc8 = ((tid & 7) ^ (lrow & 7)) << 3;     // swizzled k-chunk
    const ushort* Ag = A + (size_t)(m0 + lrow) * 1024 + lc8;
    const ushort* Bg = W + (size_t)(n0 + lrow) * 1024 + lc8;
    ushort* const sA0 = smem;
    ushort* const sB0 = smem + 16384;
    ushort* const sA1 = smem + 32768;
    ushort* const sB1 = smem + 49152;
    const int srow64 = (wv << 3) * 64;                 // wave's LDS row base

    // ---- frag addressing: phys chunk = logical ^ (row&7); byte addrs
    const int l15 = lane & 15, kq = lane >> 4, r7 = l15 & 7;
    const int wM = wv >> 2, wN = wv & 3;               // 2M x 4N waves
    const unsigned sbase = (unsigned)(unsigned long long)&smem[0];
    const unsigned pc0B = (unsigned)((kq ^ r7) << 4);
    const unsigned pc1B = pc0B ^ 64u;                  // chunk ^= 4 (ks=1)
    const unsigned aRowB = (unsigned)((wM * 128 + l15) * 128);
    const unsigned bRowB = (unsigned)((wN * 64 + l15) * 128);
    const unsigned aA0p0 = sbase + aRowB + pc0B;
    const unsigned aA0p1 = sbase + aRowB + pc1B;
    const unsigned aA1p0 = aA0p0 + 65536u;
    const unsigned aA1p1 = aA0p1 + 65536u;
    const unsigned bB0p0 = sbase + 32768u + bRowB + pc0B;
    const unsigned bB0p1 = sbase + 32768u + bRowB + pc1B;
    const unsigned bB1p0 = bB0p0 + 65536u;
    const unsigned bB1p1 = bB0p1 + 65536u;

    auto stA = [&](int buf, int h, int kt) {           // stage A half-tile
        ushort* b = buf ? sA1 : sA0;
#pragma unroll
        for (int c = 0; c < 2; ++c)
            g2l16(Ag + (size_t)(h * 128 + c * 64) * 1024 + kt * 64,
                  b + (h * 128 + c * 64) * 64 + srow64);
    };
    auto stB = [&](int buf, int h, int kt) {           // stage B half-tile
        ushort* b = buf ? sB1 : sB0;
#pragma unroll
        for (int c = 0; c < 2; ++c)
            g2l16(Bg + (size_t)(h * 128 + c * 64) * 1024 + kt * 64,
                  b + (h * 128 + c * 64) * 64 + srow64);
    };

    f32x4 acc[8][4];
#pragma unroll
    for (int i = 0; i < 8; ++i)
#pragma unroll
        for (int j = 0; j < 4; ++j)
#pragma unroll
            for (int r = 0; r < 4; ++r) acc[i][j][r] = 0.f;

    // W3 -> LDS + bias -> regs (issued BEFORE staging; prologue vmcnt(4)
    // waits them + buf0, leaving buf1.B's 4 glls in flight).
#pragma unroll
    for (int i = 0; i < 2; ++i) {
        int idx = tid + i * 512;
        w3s[(idx >> 8) * 260 + (idx & 255)] = W3[(size_t)(idx >> 8) * 2048 + n0 + (idx & 255)];
    }
    float bias4[4];
#pragma unroll
    for (int ni = 0; ni < 4; ++ni) bias4[ni] = bias[n0 + wN * 64 + ni * 16 + l15];

    // prologue: buf0 (kt 0) full + buf1.B (kt 1); buf1.A comes from P1/P2.
    stA(0, 0, 0); stA(0, 1, 0); stB(0, 0, 0); stB(0, 1, 0);
    stB(1, 0, 1); stB(1, 1, 1);
    asm volatile("s_waitcnt lgkmcnt(0)");              // w3s ds_writes drained
    VMC(4);
    SBAR(); SCHED0();

    bf16x8 afr[8], b0r[4], b1r[4];
    // P1s0 preload: aLo-ks0 + b0-ks0 (6 reads)
    afr[0] = dsr<0>(aA0p0);    afr[2] = dsr<2048>(aA0p0);
    afr[4] = dsr<4096>(aA0p0); afr[6] = dsr<6144>(aA0p0);
    b0r[0] = dsr<0>(bB0p0);    b0r[2] = dsr<2048>(bB0p0);

#pragma unroll 1
    for (int it = 0; it < 8; ++it) {
        const int k1 = 2 * it + 1, k2 = 2 * it + 2, k3 = 2 * it + 3;
        const bool nl = (it < 7);
        // ---- P1: quad(0,0) buf0 (aLo+b0) ----
        SBAR(); SCHED0();
        afr[1] = dsr<0>(aA0p1);    afr[3] = dsr<2048>(aA0p1);
        afr[5] = dsr<4096>(aA0p1); afr[7] = dsr<6144>(aA0p1);
        b0r[1] = dsr<0>(bB0p1);    b0r[3] = dsr<2048>(bB0p1);
        stA(1, 0, k1);
        LGKM(6); PRIO1(); mma_sub<0, 0, 0>(acc, afr, b0r); PRIO0();
        b1r[0] = dsr<4096>(bB0p0); b1r[2] = dsr<6144>(bB0p0);
        LGKM(2); PRIO1(); mma_sub<0, 0, 1>(acc, afr, b0r); PRIO0();
        // ---- P2: quad(0,1) buf0 (aLo+b1) ----
        SBAR(); SCHED0();
        b1r[1] = dsr<4096>(bB0p1); b1r[3] = dsr<6144>(bB0p1);
        stA(1, 1, k1);
        LGKM(2); PRIO1(); mma_sub<0, 1, 0>(acc, afr, b1r); PRIO0();
        afr[0] = dsr<8192>(aA0p0);  afr[2] = dsr<10240>(aA0p0);
        afr[4] = dsr<12288>(aA0p0); afr[6] = dsr<14336>(aA0p0);
        LGKM(4); PRIO1(); mma_sub<0, 1, 1>(acc, afr, b1r); PRIO0();
        // ---- P3: quad(1,1) buf0 (aHi+b1) ----
        SBAR(); SCHED0();
        afr[1] = dsr<8192>(aA0p1);  afr[3] = dsr<10240>(aA0p1);
        afr[5] = dsr<12288>(aA0p1); afr[7] = dsr<14336>(aA0p1);
        if (nl) stB(0, 0, k2);
        LGKM(4); PRIO1(); mma_sub<1, 1, 0>(acc, afr, b1r); PRIO0();
        LGKM(0); PRIO1(); mma_sub<1, 1, 1>(acc, afr, b1r); PRIO0();
        // ---- P4: quad(1,0) buf0 (aHi+b0) | K-tile boundary ----
        if (nl) { VMC(2); } else { VMC(0); }
        SBAR(); SCHED0();
        if (nl) stB(0, 1, k2);
        PRIO1(); mma_sub<1, 0, 0>(acc, afr, b0r); PRIO0();
        afr[0] = dsr<8192>(aA1p0);  afr[2] = dsr<10240>(aA1p0);
        afr[4] = dsr<12288>(aA1p0); afr[6] = dsr<14336>(aA1p0);
        b0r[0] = dsr<0>(bB1p0);     b0r[2] = dsr<2048>(bB1p0);
        PRIO1(); mma_sub<1, 0, 1>(acc, afr, b0r); PRIO0();
        // ---- P5: quad(1,0) buf1 (aHi1+b0_1) ----
        SBAR(); SCHED0();
        afr[1] = dsr<8192>(aA1p1);  afr[3] = dsr<10240>(aA1p1);
        afr[5] = dsr<12288>(aA1p1); afr[7] = dsr<14336>(aA1p1);
        b0r[1] = dsr<0>(bB1p1);     b0r[3] = dsr<2048>(bB1p1);
        if (nl) stA(0, 0, k2);
        LGKM(6); PRIO1(); mma_sub<1, 0, 0>(acc, afr, b0r); PRIO0();
        b1r[0] = dsr<4096>(bB1p0); b1r[2] = dsr<6144>(bB1p0);
        LGKM(2); PRIO1(); mma_sub<1, 0, 1>(acc, afr, b0r); PRIO0();
        // ---- P6: quad(1,1) buf1 ----
        SBAR(); SCHED0();
        b1r[1] = dsr<4096>(bB1p1); b1r[3] = dsr<6144>(bB1p1);
        if (nl) stA(0, 1, k2);
        LGKM(2); PRIO1(); mma_sub<1, 1, 0>(acc, afr, b1r); PRIO0();
        afr[0] = dsr<0>(aA1p0);    afr[2] = dsr<2048>(aA1p0);
        afr[4] = dsr<4096>(aA1p0); afr[6] = dsr<6144>(aA1p0);
        LGKM(4); PRIO1(); mma_sub<1, 1, 1>(acc, afr, b1r); PRIO0();
        // ---- P7: quad(0,1) buf1 (aLo1+b1_1) ----
        SBAR(); SCHED0();
        afr[1] = dsr<0>(aA1p1);    afr[3] = dsr<2048>(aA1p1);
        afr[5] = dsr<4096>(aA1p1); afr[7] = dsr<6144>(aA1p1);
        if (nl) stB(1, 0, k3);
        LGKM(4); PRIO1(); mma_sub<0, 1, 0>(acc, afr, b1r); PRIO0();
        LGKM(0); PRIO1(); mma_sub<0, 1, 1>(acc, afr, b1r); PRIO0();
        // ---- P8: quad(0,0) buf1 (aLo1+b0_1) | boundary ----
        VMC(2);
        SBAR(); SCHED0();
        if (nl) stB(1, 1, k3);
        PRIO1(); mma_sub<0, 0, 0>(acc, afr, b0r); PRIO0();
        if (nl) {   // P1s0 of next iter (buf0, k2)
            afr[0] = dsr<0>(aA0p0);    afr[2] = dsr<2048>(aA0p0);
            afr[4] = dsr<4096>(aA0p0); afr[6] = dsr<6144>(aA0p0);
            b0r[0] = dsr<0>(bB0p0);    b0r[2] = dsr<2048>(bB0p0);
        }
        PRIO1(); mma_sub<0, 0, 1>(acc, afr, b0r); PRIO0();
    }

    // ---- fused relu + W3 epilogue: 4 slab passes over Cs[64][260] f32 ----
    float* Cs = (float*)smem;
    const int drow = tid >> 3;            // 0..63
    const int cls = (tid & 7) >> 1;       // 0..3
    const int hf = tid & 1;               // col half
    const float* wrow = &w3s[cls * 260 + hf * 128];
    __syncthreads();
#pragma unroll
    for (int s = 0; s < 4; ++s) {
        if (wM == (s >> 1)) {
            const int mb = (s & 1) * 4;
#pragma unroll
            for (int mi = 0; mi < 4; ++mi)
#pragma unroll
                for (int ni = 0; ni < 4; ++ni) {
                    f32x4 v = acc[mb + mi][ni];
                    const int cbase = (mi * 16 + kq * 4) * 260 + wN * 64 + ni * 16 + l15;
#pragma unroll
                    for (int r = 0; r < 4; ++r)
                        Cs[cbase + r * 260] = fmaxf(v[r] + bias4[ni], 0.f);
                }
        }
        __syncthreads();
        {
            const float* crow = &Cs[drow * 260 + hf * 128];
            float p = 0.f;
#pragma unroll
            for (int ch = 0; ch < 64; ++ch) {
                f32x2 cv = *(const f32x2*)(crow + ch * 2);
                f32x2 wv2 = *(const f32x2*)(wrow + ch * 2);
                p += cv.x * wv2.x + cv.y * wv2.y;
            }
            p += __shfl_xor(p, 1);
            if (hf == 0)
                atomicAdd(&outf[(size_t)(m0 + s * 64 + drow) * 4 + cls], p);
        }
        __syncthreads();
    }
}

// -------------------------------------------------------------- launch ----
extern "C" void kernel_launch(void* const* d_in, const int* in_sizes, int n_in,
                              void* d_out, int out_size, void* d_ws, size_t ws_size,
                              hipStream_t stream) {
    const float* x = (const float*)d_in[0];
    LstmW w;
    for (int l = 0; l < 4; ++l) {
        w.wih[l] = (const float*)d_in[1 + 4 * l];
        w.whh[l] = (const float*)d_in[2 + 4 * l];
        w.bih[l] = (const float*)d_in[3 + 4 * l];
        w.bhh[l] = (const float*)d_in[4 + 4 * l];
    }
    const float* Wd1 = (const float*)d_in[17];
    const float* bd1 = (const float*)d_in[18];
    const float* Wd2 = (const float*)d_in[19];
    const float* bd2 = (const float*)d_in[20];
    const float* Wd3 = (const float*)d_in[21];
    const float* bd3 = (const float*)d_in[22];
    float* out = (float*)d_out;

    ushort* Y   = (ushort*)d_ws;
    ushort* H1  = (ushort*)((char*)d_ws + 6291456);
    ushort* W1b = (ushort*)((char*)d_ws + 39845888);
    ushort* W2b = (ushort*)((char*)d_ws + 40239104);

    pre_kernel<<<1072, 256, 0, stream>>>(x, w, Y, Wd1, Wd2, W1b, W2b, bd3, out);
    gemm1_kernel<<<dim3(128, 8), 256, 0, stream>>>(Y, W1b, bd1, H1, 1024);
    gemm2_kernel<<<512, 512, 0, stream>>>(H1, W2b, bd2, Wd3, out);
}

// Round 4
// 205.585 us; speedup vs baseline: 1.1164x; 1.0216x over previous
//
#include <hip/hip_runtime.h>
#include <hip/hip_bf16.h>

// LSTM_80960133529703: B=16384, T=24, F=7, H=8, L=4; dense 192->1024->2048->4.
// R12: gemm2 keeps R11's half-phase-ahead lgkm pipeline; two changes:
//  (1) stage reordering for DEEP vmcnt cover: stages P1:A1h1(k1) P3:B0h0(k2)
//      P4:B0h1+A0h0(k2) P5:A0h1(k2) P7:B1h0(k3) P8:B1h1+A1h0(k3).
//      WAR: every stage has >=1 barrier after its region's last old read
//      (B0 reads end P2h; A0 end P3h; B1 end P6h; A1 end P7h).
//      RAW: every half-tile staged >=3 phases before the wait that covers it.
//      vmcnt events/wave: P1:2 P3:2 P4:4 P5:2 P7:2 P8:4 (16/iter).
//      @P4h outstanding prevP7(2)+prevP8(4)+P1(2)+P3(2)=10 -> VMC(2) lands
//      buf1 kt2i+1, leaves P3. @P8h P3(2)+P4(4)+P5(2)+P7(2)=10 -> VMC(2)
//      lands buf0 kt2i+2, leaves P7. it7: VMC(0)@P4 (P1 ran, P3.. skipped),
//      no VMC@P8. Prologue: buf0(8)+B1h0,B1h1,A1h0(6)=14, VMC(6).
//  (2) epilogue de-broadcast: lane j8=tid&7 owns cols {j8*4+32k}, reads Cs
//      once (f32x4, bank=4*drow+4*j8 clean), 4 outputs per read, 8-lane
//      shfl_xor reduce, 1 atomic per (row,cls). 16x fewer Cs reads.
// ws: Y @0 | H1 @6291456 | W1b @39845888 | W2b @40239104
typedef __attribute__((ext_vector_type(4))) float f32x4;
typedef __attribute__((ext_vector_type(16))) float f32x16;
typedef __attribute__((ext_vector_type(2))) float f32x2;
typedef __attribute__((ext_vector_type(8))) short bf16x8;

__device__ __forceinline__ ushort f2bf(float f) {
    union { float f; uint u; } v; v.f = f;
    uint u = v.u;
    return (ushort)((u + 0x7fffu + ((u >> 16) & 1u)) >> 16);   // RNE
}
__device__ __forceinline__ float sigm(float x) {
    return __builtin_amdgcn_rcpf(1.0f + __builtin_amdgcn_exp2f(x * -1.442695040888963f));
}
__device__ __forceinline__ float tanh_(float x) {
    return 2.0f * __builtin_amdgcn_rcpf(1.0f + __builtin_amdgcn_exp2f(x * -2.885390081777927f)) - 1.0f;
}

typedef const __attribute__((address_space(1))) unsigned int ga_u32;
typedef __attribute__((address_space(3))) unsigned int lds_u32;
__device__ __forceinline__ void g2l16(const void* g, void* l) {
    __builtin_amdgcn_global_load_lds((ga_u32*)(unsigned long long)g,
                                     (lds_u32*)(unsigned int)(unsigned long long)l,
                                     16, 0, 0);
}

// ---------------------------------------------------------------- LSTM ----
struct LstmW {
    const float* wih[4];
    const float* whh[4];
    const float* bih[4];
    const float* bhh[4];
};

__device__ __forceinline__ void gates8p(const f32x2 w01[8], const f32x2 w23[8],
                                        const float xv8[8], f32x2& a01, f32x2& a23) {
#pragma unroll
    for (int k = 0; k < 8; ++k) {
        f32x2 xv = {xv8[k], xv8[k]};
        a01 += w01[k] * xv;
        a23 += w23[k] * xv;
    }
}
__device__ __forceinline__ void cellup(f32x2 a01, f32x2 a23, float& h, float& c) {
    c = sigm(a01.y) * c + sigm(a01.x) * tanh_(a23.x);
    h = sigm(a23.y) * tanh_(c);
}
__device__ __forceinline__ void ld8(const float* p, float v[8]) {
    float4 a = *(const float4*)p;
    float4 b = *(const float4*)(p + 4);
    v[0] = a.x; v[1] = a.y; v[2] = a.z; v[3] = a.w;
    v[4] = b.x; v[5] = b.y; v[6] = b.z; v[7] = b.w;
}

// blocks [0,512): LSTM; blocks [512, 512+560): weight cvt fp32->bf16 (+ out init)
__global__ __launch_bounds__(256) void pre_kernel(const float* __restrict__ x, LstmW p,
                                                  ushort* __restrict__ Y,
                                                  const float* __restrict__ W1,
                                                  const float* __restrict__ W2,
                                                  ushort* __restrict__ W1b,
                                                  ushort* __restrict__ W2b,
                                                  const float* __restrict__ b3,
                                                  float* __restrict__ out) {
    __shared__ float xs[32 * 168];
    __shared__ float hb[32 * 200];

    const int tid = threadIdx.x;
    if (blockIdx.x >= 512) {
        const int tg = (blockIdx.x - 512) * 256 + tid;
        if (tg < 16384) {
            float4 bv = {b3[0], b3[1], b3[2], b3[3]};
            ((float4*)out)[tg] = bv;
        }
#pragma unroll
        for (int s = 0; s < 4; ++s) {
            int i = tg + s * 143360;
            const float4* src; ushort4* dst; int off;
            if (i < 49152) { src = (const float4*)W1; dst = (ushort4*)W1b; off = i; }
            else { src = (const float4*)W2; dst = (ushort4*)W2b; off = i - 49152; }
            float4 v = src[off];
            ushort4 r; r.x = f2bf(v.x); r.y = f2bf(v.y); r.z = f2bf(v.z); r.w = f2bf(v.w);
            dst[off] = r;
        }
        return;
    }

    const int e0 = blockIdx.x * 32;
    {
        const float4* s = (const float4*)(x + (size_t)e0 * 168);
        float4* d = (float4*)xs;
        for (int i = tid; i < 1344; i += 256) d[i] = s[i];
    }
    __syncthreads();

    const int el = tid >> 3, j = tid & 7;
    float* hr = hb + el * 200;
    const float* xr = xs + el * 168;

    f32x2 wx01[8], wx23[8], wh01[8], wh23[8], b01, b23;

    // ---- layer 0 (in = 7) ----
    {
        const float* Wih = p.wih[0];
        const float* Whh = p.whh[0];
#pragma unroll
        for (int k = 0; k < 7; ++k) {
            wx01[k] = {Wih[(0 + j) * 7 + k], Wih[(8 + j) * 7 + k]};
            wx23[k] = {Wih[(16 + j) * 7 + k], Wih[(24 + j) * 7 + k]};
        }
#pragma unroll
        for (int k = 0; k < 8; ++k) {
            wh01[k] = {Whh[(0 + j) * 8 + k], Whh[(8 + j) * 8 + k]};
            wh23[k] = {Whh[(16 + j) * 8 + k], Whh[(24 + j) * 8 + k]};
        }
        b01 = {p.bih[0][j] + p.bhh[0][j], p.bih[0][8 + j] + p.bhh[0][8 + j]};
        b23 = {p.bih[0][16 + j] + p.bhh[0][16 + j], p.bih[0][24 + j] + p.bhh[0][24 + j]};

        float h = 0.f, c = 0.f;
        {
            f32x2 a01 = b01, a23 = b23;
#pragma unroll
            for (int k = 0; k < 7; ++k) {
                f32x2 xv = {xr[k], xr[k]};
                a01 += wx01[k] * xv; a23 += wx23[k] * xv;
            }
            cellup(a01, a23, h, c);
            hr[j] = h;
        }
        for (int t = 1; t < 24; ++t) {
            f32x2 a01 = b01, a23 = b23;
#pragma unroll
            for (int k = 0; k < 7; ++k) {
                f32x2 xv = {xr[t * 7 + k], xr[t * 7 + k]};
                a01 += wx01[k] * xv; a23 += wx23[k] * xv;
            }
            float hp[8]; ld8(&hr[(t - 1) * 8], hp);
            gates8p(wh01, wh23, hp, a01, a23);
            cellup(a01, a23, h, c);
            hr[t * 8 + j] = h;
        }
    }

    // ---- layers 1..3 ----
#pragma unroll
    for (int l = 1; l < 4; ++l) {
        const float* Wih = p.wih[l];
        const float* Whh = p.whh[l];
#pragma unroll
        for (int k = 0; k < 8; ++k) {
            wx01[k] = {Wih[(0 + j) * 8 + k], Wih[(8 + j) * 8 + k]};
            wx23[k] = {Wih[(16 + j) * 8 + k], Wih[(24 + j) * 8 + k]};
            wh01[k] = {Whh[(0 + j) * 8 + k], Whh[(8 + j) * 8 + k]};
            wh23[k] = {Whh[(16 + j) * 8 + k], Whh[(24 + j) * 8 + k]};
        }
        b01 = {p.bih[l][j] + p.bhh[l][j], p.bih[l][8 + j] + p.bhh[l][8 + j]};
        b23 = {p.bih[l][16 + j] + p.bhh[l][16 + j], p.bih[l][24 + j] + p.bhh[l][24 + j]};

        float h = 0.f, c = 0.f;
        {
            float xin[8]; ld8(&hr[0], xin);
            f32x2 a01 = b01, a23 = b23;
            gates8p(wx01, wx23, xin, a01, a23);
            cellup(a01, a23, h, c);
            hr[j] = h;
            if (l == 3) Y[((size_t)(e0 + el) * 24) * 8 + j] = f2bf(h);
        }
        for (int t = 1; t < 24; ++t) {
            float xin[8]; ld8(&hr[t * 8], xin);
            float hp[8];  ld8(&hr[(t - 1) * 8], hp);
            f32x2 a01 = b01, a23 = b23;
            gates8p(wx01, wx23, xin, a01, a23);
            gates8p(wh01, wh23, hp, a01, a23);
            cellup(a01, a23, h, c);
            hr[t * 8 + j] = h;
            if (l == 3) Y[((size_t)(e0 + el) * 24 + t) * 8 + j] = f2bf(h);
        }
    }
}

// ------------------------------------------------------- gemm1 (K=192) ----
// Tile 128x128, BK=64, 4 waves; wave tile 64x64 as 2x2 of mfma_32x32x16.
template <int KDIM>
__device__ __forceinline__ void gemm_body(const ushort* __restrict__ A,
                                          const ushort* __restrict__ W,
                                          const float* __restrict__ bias,
                                          ushort* __restrict__ Hout, int N) {
    __shared__ alignas(16) ushort smem[16384];
    ushort* As = smem;            // [128][64] swizzled
    ushort* Ws = smem + 8192;

    const int tid = threadIdx.x;
    const int m0 = blockIdx.x * 128;
    const int n0 = blockIdx.y * 128;
    const int lane = tid & 63;
    const int wv = tid >> 6;
    const int wm = (wv & 1) * 64;
    const int wn = (wv >> 1) * 64;
    const int l31 = lane & 31;
    const int kh = lane >> 5;

    // staging: per wave, 4 calls/tensor; call c: rows wv*32 + c*8 + lrow
    const int lrow = lane >> 3;
    const int lchunk = (lane & 7) ^ lrow;          // XOR swizzle at source
    const ushort* Ag = A + (size_t)(m0 + wv * 32 + lrow) * KDIM + lchunk * 8;
    const ushort* Wg = W + (size_t)(n0 + wv * 32 + lrow) * KDIM + lchunk * 8;
    ushort* Ald = As + wv * 2048;
    ushort* Wld = Ws + wv * 2048;

    const int r7 = l31 & 7;
    const int arow0 = (wm + l31) * 64;        // mi=0; mi=1 adds 32*64
    const int brow0 = (wn + l31) * 64;

    f32x16 acc[2][2];
#pragma unroll
    for (int mi = 0; mi < 2; ++mi)
#pragma unroll
        for (int ni = 0; ni < 2; ++ni)
#pragma unroll
            for (int r = 0; r < 16; ++r) acc[mi][ni][r] = 0.f;

    for (int k0 = 0; k0 < KDIM; k0 += 64) {
#pragma unroll
        for (int c = 0; c < 4; ++c)
            g2l16(Ag + (size_t)c * 8 * KDIM + k0, Ald + c * 512);
#pragma unroll
        for (int c = 0; c < 4; ++c)
            g2l16(Wg + (size_t)c * 8 * KDIM + k0, Wld + c * 512);
        __syncthreads();

#pragma unroll
        for (int ks = 0; ks < 4; ++ks) {
            const int ck = ((ks * 2 + kh) ^ r7) * 8;
            bf16x8 afr[2], bfr[2];
#pragma unroll
            for (int mi = 0; mi < 2; ++mi)
                afr[mi] = *(const bf16x8*)&As[arow0 + mi * 2048 + ck];
#pragma unroll
            for (int ni = 0; ni < 2; ++ni)
                bfr[ni] = *(const bf16x8*)&Ws[brow0 + ni * 2048 + ck];
#pragma unroll
            for (int mi = 0; mi < 2; ++mi)
#pragma unroll
                for (int ni = 0; ni < 2; ++ni)
                    acc[mi][ni] = __builtin_amdgcn_mfma_f32_32x32x16_bf16(afr[mi], bfr[ni],
                                                                         acc[mi][ni], 0, 0, 0);
        }
        __syncthreads();
    }

#pragma unroll
    for (int ni = 0; ni < 2; ++ni) {
        const int col = n0 + wn + ni * 32 + l31;
        const float b = bias[col];
#pragma unroll
        for (int mi = 0; mi < 2; ++mi)
#pragma unroll
            for (int r = 0; r < 16; ++r) {
                const int row = m0 + wm + mi * 32 + (r & 3) + 8 * (r >> 2) + 4 * kh;
                Hout[(size_t)row * N + col] = f2bf(fmaxf(acc[mi][ni][r] + b, 0.f));
            }
    }
}

__global__ __launch_bounds__(256, 4) void gemm1_kernel(const ushort* __restrict__ A,
                                                       const ushort* __restrict__ W,
                                                       const float* __restrict__ bias,
                                                       ushort* __restrict__ Hout, int N) {
    gemm_body<192>(A, W, bias, Hout, N);
}

// ---------------------------------------------- gemm2: 256^2 8-phase -----
template <int OFFB>
__device__ __forceinline__ bf16x8 dsr(unsigned a) {
    bf16x8 r;
    asm volatile("ds_read_b128 %0, %1 offset:%2"
                 : "=v"(r) : "v"(a), "i"(OFFB));
    return r;
}
// one 8-MFMA sub-cluster: quad (QA,QB), k-slice KS
template <int QA, int QB, int KS>
__device__ __forceinline__ void mma_sub(f32x4 acc[8][4], const bf16x8 afr[8],
                                        const bf16x8 br[4]) {
#pragma unroll
    for (int mi = 0; mi < 4; ++mi)
#pragma unroll
        for (int ni = 0; ni < 2; ++ni)
            acc[QA * 4 + mi][QB * 2 + ni] = __builtin_amdgcn_mfma_f32_16x16x32_bf16(
                afr[mi * 2 + KS], br[ni * 2 + KS], acc[QA * 4 + mi][QB * 2 + ni],
                0, 0, 0);
}

#define SBAR()  __builtin_amdgcn_s_barrier()
#define SCHED0() __builtin_amdgcn_sched_barrier(0)
#define LGKM(N) do { asm volatile("s_waitcnt lgkmcnt(" #N ")"); SCHED0(); } while (0)
#define VMC(N)  do { asm volatile("s_waitcnt vmcnt(" #N ")" ::: "memory"); } while (0)
#define PRIO1() __builtin_amdgcn_s_setprio(1)
#define PRIO0() do { __builtin_amdgcn_s_setprio(0); SCHED0(); } while (0)

__global__ __launch_bounds__(512) void gemm2_kernel(const ushort* __restrict__ A,
                                                    const ushort* __restrict__ W,
                                                    const float* __restrict__ bias,
                                                    const float* __restrict__ W3,
                                                    float* __restrict__ outf) {
    // LDS: 2 K-tile double buffer, [256 rows][64 k] bf16 per tensor per buf.
    // A0 @0, B0 @32768, A1 @65536, B1 @98304 (byte offsets). 128 KiB.
    __shared__ alignas(16) ushort smem[65536];
    __shared__ alignas(16) float w3s[1040];   // W3[4][256] at pitch 260

    const int tid = threadIdx.x;
    // bijective XCD swizzle (512 % 8 == 0)
    const int wg = ((int)blockIdx.x & 7) * 64 + ((int)blockIdx.x >> 3);
    const int m0 = (wg >> 3) << 8;
    const int n0 = (wg & 7) << 8;

    const int lane = tid & 63;
    const int wv = tid >> 6;

    // ---- staging addressing (pre-swizzled global source, linear LDS dest)
    const int lrow = tid >> 3;                         // 0..63 rows per call
    const int lc8 = ((tid & 7) ^ (lrow & 7)) << 3;     // swizzled k-chunk
    const ushort* Ag = A + (size_t)(m0 + lrow) * 1024 + lc8;
    const ushort* Bg = W + (size_t)(n0 + lrow) * 1024 + lc8;
    ushort* const sA0 = smem;
    ushort* const sB0 = smem + 16384;
    ushort* const sA1 = smem + 32768;
    ushort* const sB1 = smem + 49152;
    const int srow64 = (wv << 3) * 64;                 // wave's LDS row base

    // ---- frag addressing: phys chunk = logical ^ (row&7); byte addrs
    const int l15 = lane & 15, kq = lane >> 4, r7 = l15 & 7;
    const int wM = wv >> 2, wN = wv & 3;               // 2M x 4N waves
    const unsigned sbase = (unsigned)(unsigned long long)&smem[0];
    const unsigned pc0B = (unsigned)((kq ^ r7) << 4);
    const unsigned pc1B = pc0B ^ 64u;                  // chunk ^= 4 (ks=1)
    const unsigned aRowB = (unsigned)((wM * 128 + l15) * 128);
    const unsigned bRowB = (unsigned)((wN * 64 + l15) * 128);
    const unsigned aA0p0 = sbase + aRowB + pc0B;
    const unsigned aA0p1 = sbase + aRowB + pc1B;
    const unsigned aA1p0 = aA0p0 + 65536u;
    const unsigned aA1p1 = aA0p1 + 65536u;
    const unsigned bB0p0 = sbase + 32768u + bRowB + pc0B;
    const unsigned bB0p1 = sbase + 32768u + bRowB + pc1B;
    const unsigned bB1p0 = bB0p0 + 65536u;
    const unsigned bB1p1 = bB0p1 + 65536u;

    auto stA = [&](int buf, int h, int kt) {           // stage A half-tile
        ushort* b = buf ? sA1 : sA0;
#pragma unroll
        for (int c = 0; c < 2; ++c)
            g2l16(Ag + (size_t)(h * 128 + c * 64) * 1024 + kt * 64,
                  b + (h * 128 + c * 64) * 64 + srow64);
    };
    auto stB = [&](int buf, int h, int kt) {           // stage B half-tile
        ushort* b = buf ? sB1 : sB0;
#pragma unroll
        for (int c = 0; c < 2; ++c)
            g2l16(Bg + (size_t)(h * 128 + c * 64) * 1024 + kt * 64,
                  b + (h * 128 + c * 64) * 64 + srow64);
    };

    f32x4 acc[8][4];
#pragma unroll
    for (int i = 0; i < 8; ++i)
#pragma unroll
        for (int j = 0; j < 4; ++j)
#pragma unroll
            for (int r = 0; r < 4; ++r) acc[i][j][r] = 0.f;

    // W3 -> LDS + bias -> regs (before staging; lgkmcnt(0) drains ds_writes)
#pragma unroll
    for (int i = 0; i < 2; ++i) {
        int idx = tid + i * 512;
        w3s[(idx >> 8) * 260 + (idx & 255)] = W3[(size_t)(idx >> 8) * 2048 + n0 + (idx & 255)];
    }
    float bias4[4];
#pragma unroll
    for (int ni = 0; ni < 4; ++ni) bias4[ni] = bias[n0 + wN * 64 + ni * 16 + l15];

    // prologue: buf0 kt0 full (8) + buf1 kt1 B both halves + A h0 (6).
    // A1h1(kt1) comes from it0's P1 stage. VMC(6) lands buf0, leaves buf1's 6.
    stA(0, 0, 0); stA(0, 1, 0); stB(0, 0, 0); stB(0, 1, 0);
    stB(1, 0, 1); stB(1, 1, 1); stA(1, 0, 1);
    asm volatile("s_waitcnt lgkmcnt(0)");              // w3s ds_writes drained
    VMC(6);
    SBAR(); SCHED0();

    bf16x8 afr[8], b0r[4], b1r[4];
    // P1s0 preload: aLo-ks0 + b0-ks0 (6 reads)
    afr[0] = dsr<0>(aA0p0);    afr[2] = dsr<2048>(aA0p0);
    afr[4] = dsr<4096>(aA0p0); afr[6] = dsr<6144>(aA0p0);
    b0r[0] = dsr<0>(bB0p0);    b0r[2] = dsr<2048>(bB0p0);

#pragma unroll 1
    for (int it = 0; it < 8; ++it) {
        const int k1 = 2 * it + 1, k2 = 2 * it + 2, k3 = 2 * it + 3;
        const bool nl = (it < 7);
        // ---- P1: quad(0,0) buf0 (aLo+b0) | stage A1h1(k1) ----
        SBAR(); SCHED0();
        afr[1] = dsr<0>(aA0p1);    afr[3] = dsr<2048>(aA0p1);
        afr[5] = dsr<4096>(aA0p1); afr[7] = dsr<6144>(aA0p1);
        b0r[1] = dsr<0>(bB0p1);    b0r[3] = dsr<2048>(bB0p1);
        stA(1, 1, k1);
        LGKM(6); PRIO1(); mma_sub<0, 0, 0>(acc, afr, b0r); PRIO0();
        b1r[0] = dsr<4096>(bB0p0); b1r[2] = dsr<6144>(bB0p0);
        LGKM(2); PRIO1(); mma_sub<0, 0, 1>(acc, afr, b0r); PRIO0();
        // ---- P2: quad(0,1) buf0 (aLo+b1) ----
        SBAR(); SCHED0();
        b1r[1] = dsr<4096>(bB0p1); b1r[3] = dsr<6144>(bB0p1);
        LGKM(2); PRIO1(); mma_sub<0, 1, 0>(acc, afr, b1r); PRIO0();
        afr[0] = dsr<8192>(aA0p0);  afr[2] = dsr<10240>(aA0p0);
        afr[4] = dsr<12288>(aA0p0); afr[6] = dsr<14336>(aA0p0);
        LGKM(4); PRIO1(); mma_sub<0, 1, 1>(acc, afr, b1r); PRIO0();
        // ---- P3: quad(1,1) buf0 (aHi+b1) | stage B0h0(k2) ----
        SBAR(); SCHED0();
        afr[1] = dsr<8192>(aA0p1);  afr[3] = dsr<10240>(aA0p1);
        afr[5] = dsr<12288>(aA0p1); afr[7] = dsr<14336>(aA0p1);
        if (nl) stB(0, 0, k2);
        LGKM(4); PRIO1(); mma_sub<1, 1, 0>(acc, afr, b1r); PRIO0();
        LGKM(0); PRIO1(); mma_sub<1, 1, 1>(acc, afr, b1r); PRIO0();
        // ---- P4: quad(1,0) buf0 (aHi+b0) | wait buf1 | stage B0h1+A0h0(k2) ----
        if (nl) { VMC(2); } else { VMC(0); }
        SBAR(); SCHED0();
        if (nl) { stB(0, 1, k2); stA(0, 0, k2); }
        PRIO1(); mma_sub<1, 0, 0>(acc, afr, b0r); PRIO0();
        afr[0] = dsr<8192>(aA1p0);  afr[2] = dsr<10240>(aA1p0);
        afr[4] = dsr<12288>(aA1p0); afr[6] = dsr<14336>(aA1p0);
        b0r[0] = dsr<0>(bB1p0);     b0r[2] = dsr<2048>(bB1p0);
        PRIO1(); mma_sub<1, 0, 1>(acc, afr, b0r); PRIO0();
        // ---- P5: quad(1,0) buf1 (aHi1+b0_1) | stage A0h1(k2) ----
        SBAR(); SCHED0();
        afr[1] = dsr<8192>(aA1p1);  afr[3] = dsr<10240>(aA1p1);
        afr[5] = dsr<12288>(aA1p1); afr[7] = dsr<14336>(aA1p1);
        b0r[1] = dsr<0>(bB1p1);     b0r[3] = dsr<2048>(bB1p1);
        if (nl) stA(0, 1, k2);
        LGKM(6); PRIO1(); mma_sub<1, 0, 0>(acc, afr, b0r); PRIO0();
        b1r[0] = dsr<4096>(bB1p0); b1r[2] = dsr<6144>(bB1p0);
        LGKM(2); PRIO1(); mma_sub<1, 0, 1>(acc, afr, b0r); PRIO0();
        // ---- P6: quad(1,1) buf1 ----
        SBAR(); SCHED0();
        b1r[1] = dsr<4096>(bB1p1); b1r[3] = dsr<6144>(bB1p1);
        LGKM(2); PRIO1(); mma_sub<1, 1, 0>(acc, afr, b1r); PRIO0();
        afr[0] = dsr<0>(aA1p0);    afr[2] = dsr<2048>(aA1p0);
        afr[4] = dsr<4096>(aA1p0); afr[6] = dsr<6144>(aA1p0);
        LGKM(4); PRIO1(); mma_sub<1, 1, 1>(acc, afr, b1r); PRIO0();
        // ---- P7: quad(0,1) buf1 (aLo1+b1_1) | stage B1h0(k3) ----
        SBAR(); SCHED0();
        afr[1] = dsr<0>(aA1p1);    afr[3] = dsr<2048>(aA1p1);
        afr[5] = dsr<4096>(aA1p1); afr[7] = dsr<6144>(aA1p1);
        if (nl) stB(1, 0, k3);
        LGKM(4); PRIO1(); mma_sub<0, 1, 0>(acc, afr, b1r); PRIO0();
        LGKM(0); PRIO1(); mma_sub<0, 1, 1>(acc, afr, b1r); PRIO0();
        // ---- P8: quad(0,0) buf1 (aLo1+b0_1) | wait buf0-k2 | stage B1h1+A1h0(k3) ----
        if (nl) { VMC(2); }
        SBAR(); SCHED0();
        if (nl) { stB(1, 1, k3); stA(1, 0, k3); }
        PRIO1(); mma_sub<0, 0, 0>(acc, afr, b0r); PRIO0();
        if (nl) {   // P1s0 of next iter (buf0, k2)
            afr[0] = dsr<0>(aA0p0);    afr[2] = dsr<2048>(aA0p0);
            afr[4] = dsr<4096>(aA0p0); afr[6] = dsr<6144>(aA0p0);
            b0r[0] = dsr<0>(bB0p0);    b0r[2] = dsr<2048>(bB0p0);
        }
        PRIO1(); mma_sub<0, 0, 1>(acc, afr, b0r); PRIO0();
    }

    // ---- fused relu + W3 epilogue: 4 slab passes over Cs[64][260] f32 ----
    // De-broadcast dot: lane j8 owns cols {j8*4 + 32k, k=0..7} (disjoint,
    // bank = 4*drow + 4*j8 -> conflict-free). One Cs read serves 4 outputs.
    float* Cs = (float*)smem;
    const int drow = tid >> 3;            // 0..63
    const int j8 = tid & 7;               // col-interleave lane
    __syncthreads();
#pragma unroll
    for (int s = 0; s < 4; ++s) {
        if (wM == (s >> 1)) {
            const int mb = (s & 1) * 4;
#pragma unroll
            for (int mi = 0; mi < 4; ++mi)
#pragma unroll
                for (int ni = 0; ni < 4; ++ni) {
                    f32x4 v = acc[mb + mi][ni];
                    const int cbase = (mi * 16 + kq * 4) * 260 + wN * 64 + ni * 16 + l15;
#pragma unroll
                    for (int r = 0; r < 4; ++r)
                        Cs[cbase + r * 260] = fmaxf(v[r] + bias4[ni], 0.f);
                }
        }
        __syncthreads();
        {
            const float* crow = &Cs[drow * 260 + j8 * 4];
            f32x4 pp = {0.f, 0.f, 0.f, 0.f};
#pragma unroll
            for (int k = 0; k < 8; ++k) {
                f32x4 cv = *(const f32x4*)(crow + k * 32);
#pragma unroll
                for (int q = 0; q < 4; ++q) {
                    f32x4 wv4 = *(const f32x4*)(&w3s[q * 260 + j8 * 4 + k * 32]);
                    pp[q] += cv[0] * wv4[0] + cv[1] * wv4[1] + cv[2] * wv4[2] + cv[3] * wv4[3];
                }
            }
#pragma unroll
            for (int m = 1; m < 8; m <<= 1) {
#pragma unroll
                for (int q = 0; q < 4; ++q) pp[q] += __shfl_xor(pp[q], m);
            }
            const float pv = (j8 == 0) ? pp[0] : (j8 == 1) ? pp[1]
                           : (j8 == 2) ? pp[2] : pp[3];
            if (j8 < 4)
                atomicAdd(&outf[(size_t)(m0 + s * 64 + drow) * 4 + j8], pv);
        }
        __syncthreads();
    }
}

// -------------------------------------------------------------- launch ----
extern "C" void kernel_launch(void* const* d_in, const int* in_sizes, int n_in,
                              void* d_out, int out_size, void* d_ws, size_t ws_size,
                              hipStream_t stream) {
    const float* x = (const float*)d_in[0];
    LstmW w;
    for (int l = 0; l < 4; ++l) {
        w.wih[l] = (const float*)d_in[1 + 4 * l];
        w.whh[l] = (const float*)d_in[2 + 4 * l];
        w.bih[l] = (const float*)d_in[3 + 4 * l];
        w.bhh[l] = (const float*)d_in[4 + 4 * l];
    }
    const float* Wd1 = (const float*)d_in[17];
    const float* bd1 = (const float*)d_in[18];
    const float* Wd2 = (const float*)d_in[19];
    const float* bd2 = (const float*)d_in[20];
    const float* Wd3 = (const float*)d_in[21];
    const float* bd3 = (const float*)d_in[22];
    float* out = (float*)d_out;

    ushort* Y   = (ushort*)d_ws;
    ushort* H1  = (ushort*)((char*)d_ws + 6291456);
    ushort* W1b = (ushort*)((char*)d_ws + 39845888);
    ushort* W2b = (ushort*)((char*)d_ws + 40239104);

    pre_kernel<<<1072, 256, 0, stream>>>(x, w, Y, Wd1, Wd2, W1b, W2b, bd3, out);
    gemm1_kernel<<<dim3(128, 8), 256, 0, stream>>>(Y, W1b, bd1, H1, 1024);
    gemm2_kernel<<<512, 512, 0, stream>>>(H1, W2b, bd2, Wd3, out);
}